// Round 7
// baseline (355.827 us; speedup 1.0000x reference)
//
#include <hip/hip_runtime.h>
#include <cstdint>
#include <cstddef>

#define B_    16
#define S_    1024
#define DIM_  1024
#define H_    16
#define HD_   64
#define TDIM  3072   // 3*DIM

typedef unsigned short ushort_t;
typedef unsigned int   uint_t;
typedef __attribute__((ext_vector_type(8))) short s8v;   // 8 bf16 = 4 VGPRs
typedef __attribute__((ext_vector_type(4))) float f32x4;

__device__ __forceinline__ float b2f(ushort_t u) {
    union { uint_t i; float f; } t; t.i = (uint_t)u << 16; return t.f;
}
__device__ __forceinline__ ushort_t f2b(float f) {
    union { float f; uint_t i; } t; t.f = f;
    uint_t r = t.i + 0x7FFFu + ((t.i >> 16) & 1u);   // RNE
    return (ushort_t)(r >> 16);
}
__device__ __forceinline__ uint_t cvt_pk_bf16(float a, float b) {
    uint_t r;
    asm("v_cvt_pk_bf16_f32 %0, %1, %2" : "=v"(r) : "v"(a), "v"(b));
    return r;
}

// D[m][n] += sum_k A[m,k]*B[k,n].
// A-frag: lane&15=m, (lane>>4)*8+j=k. B-frag: lane&15=n, same k.
// D-frag (HW-verified m89/m91): col=lane&15, row=(lane>>4)*4+reg.
__device__ __forceinline__ f32x4 mfma_bf16(s8v a, s8v b, f32x4 c) {
    asm volatile("v_mfma_f32_16x16x32_bf16 %0, %1, %2, %0" : "+v"(c) : "v"(a), "v"(b));
    return c;
}

// async global->LDS, 16B per lane; LDS dest = wave-uniform base + lane*16.
__device__ __forceinline__ void gload16(const void* g, void* l) {
    __builtin_amdgcn_global_load_lds(
        (const __attribute__((address_space(1))) uint_t*)g,
        (__attribute__((address_space(3))) uint_t*)l, 16, 0, 0);
}

// raw barrier with compile-time memory fences (no vmcnt drain!)
__device__ __forceinline__ void bar() {
    asm volatile("" ::: "memory");
    __builtin_amdgcn_s_barrier();
    asm volatile("" ::: "memory");
}
__device__ __forceinline__ void wait_vm0() {
    asm volatile("s_waitcnt vmcnt(0)" ::: "memory");
}

// ---------------------------------------------------------------------------
// fp32 -> bf16, 8 elements/thread
// ---------------------------------------------------------------------------
__global__ __launch_bounds__(256) void f32_to_bf16_vec(const float* __restrict__ src,
                                                       short* __restrict__ dst, int n8) {
    int i = blockIdx.x * 256 + threadIdx.x;
    if (i < n8) {
        float4 a = *(const float4*)(src + (size_t)i * 8);
        float4 b = *(const float4*)(src + (size_t)i * 8 + 4);
        s8v t;
        t[0] = (short)f2b(a.x); t[1] = (short)f2b(a.y);
        t[2] = (short)f2b(a.z); t[3] = (short)f2b(a.w);
        t[4] = (short)f2b(b.x); t[5] = (short)f2b(b.y);
        t[6] = (short)f2b(b.z); t[7] = (short)f2b(b.w);
        *(s8v*)(dst + (size_t)i * 8) = t;
    }
}

// ---------------------------------------------------------------------------
// RoPE cos/sin tables [S][HD] fp32
// ---------------------------------------------------------------------------
__global__ __launch_bounds__(256) void rope_tables(float* __restrict__ cos_t,
                                                   float* __restrict__ sin_t) {
    int idx = blockIdx.x * 256 + threadIdx.x;     // 0 .. 65535
    int s = idx >> 6;
    int d = idx & 63;
    int pos = (d < 32) ? (s >> 5) : (s & 31);
    int i   = (d & 31) >> 1;
    float freq  = expf(-(float)i * 0.5756462732485115f);   // ln(10000)/16
    float angle = (float)pos * 0.5f * freq;
    cos_t[idx] = cosf(angle);
    sin_t[idx] = sinf(angle);
}

// ---------------------------------------------------------------------------
// W[K][N] fp32 -> WT[N][K] bf16  (32x32 LDS tile transpose)
// ---------------------------------------------------------------------------
__global__ __launch_bounds__(256) void transpose_to_bf16(const float* __restrict__ Wsrc,
                                                         short* __restrict__ WT,
                                                         int K, int N) {
    __shared__ float t[32][33];
    int tx = threadIdx.x & 31, ty = threadIdx.x >> 5;   // ty 0..7
    int n0 = blockIdx.x * 32, k0 = blockIdx.y * 32;
#pragma unroll
    for (int i = 0; i < 4; ++i)
        t[ty + 8 * i][tx] = Wsrc[(size_t)(k0 + ty + 8 * i) * N + n0 + tx];
    __syncthreads();
#pragma unroll
    for (int i = 0; i < 4; ++i)
        WT[(size_t)(n0 + ty + 8 * i) * K + k0 + tx] = (short)f2b(t[tx][ty + 8 * i]);
}

// ---------------------------------------------------------------------------
// 8-wave 256x256 bf16 MFMA GEMM, BK=32, double-buffered LDS, pipelined with
// raw s_barrier + explicit vmcnt (no compiler vmcnt-drain at barriers).
//   C[M,N] = A[M,K] @ B[K,N] + bias, B given as BT[N,K]. A,BT bf16.
//   NORM: fused per-head RMSNorm + RoPE epilogue for columns < 2048.
// Waves: 2(M) x 4(N); per-wave output 128x64 = acc[8][4] 16x16 frags.
// K-tile loop (BK=32), 2 sub-phases: ph0 computes mi0-3, ph1 mi4-7.
// Staging: ph0 issues next tile's A (2 gloads), ph1 next tile's B.
// ---------------------------------------------------------------------------
template<typename CT, bool NORM>
__global__ __launch_bounds__(512, 2) void gemm8(
        const short* __restrict__ A, const short* __restrict__ BT,
        const float* __restrict__ bias, CT* __restrict__ C,
        int M, int N, int K, int NX,
        const float* __restrict__ qw, const float* __restrict__ kw,
        const float* __restrict__ cos_t, const float* __restrict__ sin_t) {
    __shared__ short As[2 * 256 * 32];   // 32 KiB  [buf][row256][k32]
    __shared__ short Bs[2 * 256 * 32];   // 32 KiB

    const int tid  = threadIdx.x;
    const int w    = tid >> 6;           // 0..7
    const int lane = tid & 63;
    const int l15  = lane & 15, lg = lane >> 4;
    const int wm = w >> 2, wn = w & 3;   // wave grid 2x4

    // bijective XCD-chunked remap (nwg % 8 == 0)
    const int nwg  = gridDim.x;
    const int cpx  = nwg >> 3;
    const int wgid = (blockIdx.x & 7) * cpx + (blockIdx.x >> 3);
    const int bx = wgid % NX, by = wgid / NX;
    const int m0 = by * 256, n0 = bx * 256;

    const int NT = K >> 5;               // K-tiles of 32

    // staging geometry: one gload per wave per half-tile;
    // rows h*128 + w*16 + (lane>>2), k chunk (lane&3)*8.
    const int srow = w * 16 + (lane >> 2);
    const int sk   = (lane & 3) * 8;

    auto stageA = [&](int kt, int buf) {
        int k0 = kt << 5;
#pragma unroll
        for (int h = 0; h < 2; ++h)
            gload16(A + (size_t)(m0 + h * 128 + srow) * K + k0 + sk,
                    &As[buf * 8192 + (h * 128 + w * 16) * 32]);
    };
    auto stageB = [&](int kt, int buf) {
        int k0 = kt << 5;
#pragma unroll
        for (int h = 0; h < 2; ++h)
            gload16(BT + (size_t)(n0 + h * 128 + srow) * K + k0 + sk,
                    &Bs[buf * 8192 + (h * 128 + w * 16) * 32]);
    };

    // prologue: stage tile 0 into buf 0
    stageA(0, 0);
    stageB(0, 0);

    f32x4 acc[8][4] = {};
    s8v bf[4];

    for (int kt = 0; kt < NT; ++kt) {
        const int buf  = kt & 1;
        const int nbuf = buf ^ 1;

        // K-tile boundary: own gloads done, then all waves' (barrier)
        wait_vm0();
        bar();

#pragma unroll
        for (int ph = 0; ph < 2; ++ph) {
            // ds-read this phase's register subtile (from buf)
            s8v af[4];
#pragma unroll
            for (int i = 0; i < 4; ++i)
                af[i] = *(const s8v*)&As[buf * 8192 +
                        (wm * 128 + ph * 64 + i * 16 + l15) * 32 + lg * 8];
            if (ph == 0) {
#pragma unroll
                for (int i = 0; i < 4; ++i)
                    bf[i] = *(const s8v*)&Bs[buf * 8192 +
                            (wn * 64 + i * 16 + l15) * 32 + lg * 8];
            }
            // issue next tile's staging (A at ph0, B at ph1)
            if (kt + 1 < NT) {
                if (ph == 0) stageA(kt + 1, nbuf);
                else         stageB(kt + 1, nbuf);
            }
            bar();
            __builtin_amdgcn_s_setprio(1);
#pragma unroll
            for (int mi = 0; mi < 4; ++mi)
#pragma unroll
                for (int ni = 0; ni < 4; ++ni)
                    acc[ph * 4 + mi][ni] = mfma_bf16(af[mi], bf[ni], acc[ph * 4 + mi][ni]);
            __builtin_amdgcn_s_setprio(0);
            bar();
        }
    }

    // ---------------- epilogue ----------------
    const int colbase = n0 + wn * 64;
    if constexpr (NORM) {
        if (colbase < 2048) {
            const float* nw = (colbase < 1024) ? qw : kw;
            float wv[4], bv[4];
#pragma unroll
            for (int ni = 0; ni < 4; ++ni) {
                wv[ni] = nw[16 * ni + l15];
                bv[ni] = bias[colbase + 16 * ni + l15];
            }
#pragma unroll
            for (int mi = 0; mi < 8; ++mi) {
#pragma unroll
                for (int r = 0; r < 4; ++r) {
                    int row = m0 + wm * 128 + mi * 16 + lg * 4 + r;
                    int s = row & (S_ - 1);
                    float v[4];
#pragma unroll
                    for (int ni = 0; ni < 4; ++ni) v[ni] = acc[mi][ni][r] + bv[ni];
                    float ss = v[0]*v[0] + v[1]*v[1] + v[2]*v[2] + v[3]*v[3];
                    ss += __shfl_xor(ss, 1);
                    ss += __shfl_xor(ss, 2);
                    ss += __shfl_xor(ss, 4);
                    ss += __shfl_xor(ss, 8);
                    float rms = rsqrtf(ss * (1.0f / 64.0f) + 1e-6f);
                    float xn[4];
#pragma unroll
                    for (int ni = 0; ni < 4; ++ni) xn[ni] = v[ni] * rms * wv[ni];
#pragma unroll
                    for (int ni = 0; ni < 4; ++ni) {
                        int d = 16 * ni + l15;
                        float c  = cos_t[s * 64 + d];
                        float sn = sin_t[s * 64 + d];
                        float rot = (ni < 2) ? -xn[ni + 2] : xn[ni - 2];
                        C[(size_t)row * N + colbase + d] = (short)f2b(xn[ni] * c + rot * sn);
                    }
                }
            }
            return;
        }
    }
#pragma unroll
    for (int ni = 0; ni < 4; ++ni) {
        float bvv = bias[colbase + 16 * ni + l15];
#pragma unroll
        for (int mi = 0; mi < 8; ++mi) {
#pragma unroll
            for (int r = 0; r < 4; ++r) {
                size_t row = (size_t)(m0 + wm * 128 + mi * 16 + lg * 4 + r);
                int    col = colbase + 16 * ni + l15;
                float v = acc[mi][ni][r] + bvv;
                if constexpr (sizeof(CT) == 4) C[row * N + col] = v;
                else                           C[row * N + col] = (short)f2b(v);
            }
        }
    }
}

// ---------------------------------------------------------------------------
// MFMA flash attention (round-6 body) + XCD-locality block remap:
// each XCD owns a contiguous band of 32 (b,h) pairs; its 8 q-tiles per (b,h)
// reuse the band's K/V from the XCD-private L2.
// ---------------------------------------------------------------------------
__global__ __launch_bounds__(256) void attn_mfma(const short* __restrict__ qkv,
                                                 short* __restrict__ attn) {
    __shared__ ushort_t Ks[64][72];        // K-tile  [key][d]
    __shared__ ushort_t Vt[64][72];        // V-tile^T [d][key-swizzled]
    __shared__ ushort_t Ps[4][32][72];     // per-wave P [q_local][key]

    const float SC  = 0.18033688011112042f;   // 0.125 * log2(e)
    const float THR = 11.0f;                  // defer-max threshold (exp2 units)

    const int tid  = threadIdx.x;
    const int w    = tid >> 6;
    const int lane = tid & 63;
    const int l15  = lane & 15, lg = lane >> 4;

    // XCD remap: bid -> (xcd, j); bh = xcd*32 + (j&31); qt = j>>5
    const int bid = blockIdx.x;
    const int xcd = bid & 7;
    const int j   = bid >> 3;
    const int bh  = xcd * 32 + (j & 31);
    const int b   = bh >> 4, h = bh & 15;
    const int q0  = (j >> 5) * 128;

    const short* qbase = qkv + (size_t)b * S_ * TDIM + h * HD_;
    const short* kb = qbase + DIM_;
    const short* vb = qbase + 2 * DIM_;

    s8v qf[2][2];
#pragma unroll
    for (int mq = 0; mq < 2; ++mq)
#pragma unroll
        for (int kk = 0; kk < 2; ++kk)
            qf[mq][kk] = *(const s8v*)(qbase + (size_t)(q0 + w * 32 + mq * 16 + l15) * TDIM
                                       + kk * 32 + lg * 8);

    f32x4 of[2][4] = {};
    float m_s[2] = {-1e30f, -1e30f};
    float l_s[2] = {0.f, 0.f};

    const int kr   = tid >> 3;
    const int kp8  = (tid & 7) * 8;
    const int vkp  = tid >> 3;
    const int va   = tid & 7;
    const int vp8  = va * 8;
    const int vcol = (2 * vkp) ^ ((va & 3) << 4);

    s8v kA, kB, vA, vB;
    auto prefetch = [&](int kt) {
        const short* kbt = kb + (size_t)kt * 64 * TDIM;
        const short* vbt = vb + (size_t)kt * 64 * TDIM;
        kA = *(const s8v*)(kbt + (size_t)kr * TDIM + kp8);
        kB = *(const s8v*)(kbt + (size_t)(kr + 32) * TDIM + kp8);
        vA = *(const s8v*)(vbt + (size_t)(2 * vkp) * TDIM + vp8);
        vB = *(const s8v*)(vbt + (size_t)(2 * vkp + 1) * TDIM + vp8);
    };
    prefetch(0);

    for (int kt = 0; kt < 16; ++kt) {
        *(s8v*)&Ks[kr][kp8]      = kA;
        *(s8v*)&Ks[kr + 32][kp8] = kB;
#pragma unroll
        for (int jj = 0; jj < 8; ++jj) {
            uint_t pk = (ushort_t)vA[jj] | ((uint_t)(ushort_t)vB[jj] << 16);
            *(uint_t*)&Vt[vp8 + jj][vcol] = pk;
        }
        __syncthreads();

        if (kt < 15) prefetch(kt + 1);

        // ---- QK^T (swapped): st[nk][mq] = S^T[key][q] fragments (raw logits)
        f32x4 st[4][2] = {};
        __builtin_amdgcn_s_setprio(1);
#pragma unroll
        for (int kk = 0; kk < 2; ++kk) {
            s8v kf[4];
#pragma unroll
            for (int nk = 0; nk < 4; ++nk)
                kf[nk] = *(const s8v*)&Ks[nk * 16 + l15][kk * 32 + lg * 8];
#pragma unroll
            for (int nk = 0; nk < 4; ++nk)
#pragma unroll
                for (int mq = 0; mq < 2; ++mq)
                    st[nk][mq] = mfma_bf16(kf[nk], qf[mq][kk], st[nk][mq]);
        }
        __builtin_amdgcn_s_setprio(0);

        // ---- online softmax (exp2 domain, defer-max)
#pragma unroll
        for (int mq = 0; mq < 2; ++mq) {
            float mx = -1e30f;
#pragma unroll
            for (int nk = 0; nk < 4; ++nk)
#pragma unroll
                for (int r = 0; r < 4; ++r)
                    mx = fmaxf(mx, st[nk][mq][r]);
            mx = fmaxf(mx, __shfl_xor(mx, 16));
            mx = fmaxf(mx, __shfl_xor(mx, 32));
            float mxs = mx * SC;

            if (!__all(mxs <= m_s[mq] + THR)) {
                float mnew  = fmaxf(m_s[mq], mxs);
                float alpha = exp2f(m_s[mq] - mnew);
                m_s[mq] = mnew;
                l_s[mq] *= alpha;
                float a4[4];
#pragma unroll
                for (int r = 0; r < 4; ++r) a4[r] = __shfl(alpha, lg * 4 + r);
#pragma unroll
                for (int nd = 0; nd < 4; ++nd)
#pragma unroll
                    for (int r = 0; r < 4; ++r) of[mq][nd][r] *= a4[r];
            }

            float m = m_s[mq];
            float ls = 0.f;
#pragma unroll
            for (int nk = 0; nk < 4; ++nk) {
#pragma unroll
                for (int r = 0; r < 4; ++r) {
                    float p = exp2f(__builtin_fmaf(st[nk][mq][r], SC, -m));
                    st[nk][mq][r] = p;
                    ls += p;
                }
            }
            ls += __shfl_xor(ls, 16);
            ls += __shfl_xor(ls, 32);
            l_s[mq] += ls;

#pragma unroll
            for (int nk = 0; nk < 4; ++nk) {
                uint2 pk2;
                pk2.x = cvt_pk_bf16(st[nk][mq][0], st[nk][mq][1]);
                pk2.y = cvt_pk_bf16(st[nk][mq][2], st[nk][mq][3]);
                *(uint2*)&Ps[w][mq * 16 + l15][nk * 16 + lg * 4] = pk2;
            }
        }

        // ---- PV
        __builtin_amdgcn_s_setprio(1);
#pragma unroll
        for (int kk = 0; kk < 2; ++kk) {
            s8v pf[2], vf[4];
#pragma unroll
            for (int mq = 0; mq < 2; ++mq)
                pf[mq] = *(const s8v*)&Ps[w][mq * 16 + l15][kk * 32 + lg * 8];
#pragma unroll
            for (int nd = 0; nd < 4; ++nd) {
                int swz = (2 * nd + (l15 >> 3)) & 3;
                vf[nd] = *(const s8v*)&Vt[nd * 16 + l15][(kk * 32 + lg * 8) ^ (swz << 4)];
            }
#pragma unroll
            for (int mq = 0; mq < 2; ++mq)
#pragma unroll
                for (int nd = 0; nd < 4; ++nd)
                    of[mq][nd] = mfma_bf16(pf[mq], vf[nd], of[mq][nd]);
        }
        __builtin_amdgcn_s_setprio(0);
        __syncthreads();
    }

    // epilogue
#pragma unroll
    for (int mq = 0; mq < 2; ++mq) {
        float rinv = 1.0f / l_s[mq];
        float iv[4];
#pragma unroll
        for (int r = 0; r < 4; ++r) iv[r] = __shfl(rinv, lg * 4 + r);
#pragma unroll
        for (int nd = 0; nd < 4; ++nd)
#pragma unroll
            for (int r = 0; r < 4; ++r) {
                int row = q0 + w * 32 + mq * 16 + lg * 4 + r;
                attn[((size_t)b * S_ + row) * DIM_ + h * HD_ + nd * 16 + l15] =
                    (short)f2b(of[mq][nd][r] * iv[r]);
            }
    }
}

// ---------------------------------------------------------------------------
extern "C" void kernel_launch(void* const* d_in, const int* in_sizes, int n_in,
                              void* d_out, int out_size, void* d_ws, size_t ws_size,
                              hipStream_t stream) {
    const float* x        = (const float*)d_in[0];
    const float* w_qkv    = (const float*)d_in[1];
    const float* b_qkv    = (const float*)d_in[2];
    const float* q_norm_w = (const float*)d_in[3];
    const float* k_norm_w = (const float*)d_in[4];
    const float* w_out    = (const float*)d_in[5];
    const float* b_out    = (const float*)d_in[6];
    float* out = (float*)d_out;

    // workspace layout (~170 MiB)
    const size_t OFF_QKV = 0;                          //  96 MiB: qkv bf16
    const size_t OFF_ATT = 100663296;                  //  32 MiB: attn bf16
    const size_t OFF_XB  = OFF_ATT + 33554432;         //  32 MiB: x bf16
    const size_t OFF_WQ  = OFF_XB + 33554432;          //   6 MiB: w_qkv^T bf16
    const size_t OFF_WO  = OFF_WQ + 6291456;           //   2 MiB: w_out^T bf16
    const size_t OFF_CT  = OFF_WO + 2097152;           // 256 KiB: cos table
    const size_t OFF_ST  = OFF_CT + 262144;            // 256 KiB: sin table
    const size_t NEED    = OFF_ST + 262144;

    if (ws_size < NEED) {
        hipMemsetAsync(d_out, 0, (size_t)out_size * sizeof(float), stream);
        return;
    }

    char* ws = (char*)d_ws;
    short* qkv   = (short*)(ws + OFF_QKV);
    short* attnb = (short*)(ws + OFF_ATT);
    short* xb    = (short*)(ws + OFF_XB);
    short* wqkvT = (short*)(ws + OFF_WQ);
    short* woutT = (short*)(ws + OFF_WO);
    float* cos_t = (float*)(ws + OFF_CT);
    float* sin_t = (float*)(ws + OFF_ST);

    // 0: tables, conversions, weight transposes
    rope_tables<<<dim3(256), dim3(256), 0, stream>>>(cos_t, sin_t);
    f32_to_bf16_vec<<<dim3(8192), dim3(256), 0, stream>>>(x, xb, 2097152);
    transpose_to_bf16<<<dim3(96, 32), dim3(256), 0, stream>>>(w_qkv, wqkvT, 1024, 3072);
    transpose_to_bf16<<<dim3(32, 32), dim3(256), 0, stream>>>(w_out, woutT, 1024, 1024);

    // 1: qkv = x @ w_qkv + b_qkv, fused RMSNorm+RoPE epilogue on q,k columns.
    //    grid = (16384/256)*(3072/256) = 64*12 = 768 blocks (%8==0), 512 thr.
    gemm8<short, true><<<dim3(768), dim3(512), 0, stream>>>(
        xb, wqkvT, b_qkv, qkv, 16384, 3072, 1024, 12,
        q_norm_w, k_norm_w, cos_t, sin_t);

    // 2: flash attention -> attnb (bf16); 1-D grid 2048 with XCD-band remap
    attn_mfma<<<dim3(2048), dim3(256), 0, stream>>>(qkv, attnb);

    // 3: out = attn @ w_out + b_out (fp32 out); grid = 64*4 = 256 blocks
    gemm8<float, false><<<dim3(256), dim3(512), 0, stream>>>(
        attnb, woutT, b_out, out, 16384, 1024, 1024, 4,
        nullptr, nullptr, nullptr, nullptr);
}

// Round 8
// 346.360 us; speedup vs baseline: 1.0273x; 1.0273x over previous
//
#include <hip/hip_runtime.h>
#include <cstdint>
#include <cstddef>

#define B_    16
#define S_    1024
#define DIM_  1024
#define H_    16
#define HD_   64
#define TDIM  3072   // 3*DIM

typedef unsigned short ushort_t;
typedef unsigned int   uint_t;
typedef __attribute__((ext_vector_type(8)))  short s8v;    // 8 bf16 = 4 VGPRs
typedef __attribute__((ext_vector_type(4)))  float f32x4;
typedef __attribute__((ext_vector_type(16))) float f32x16;

__device__ __forceinline__ float b2f(ushort_t u) {
    union { uint_t i; float f; } t; t.i = (uint_t)u << 16; return t.f;
}
__device__ __forceinline__ ushort_t f2b(float f) {
    union { float f; uint_t i; } t; t.f = f;
    uint_t r = t.i + 0x7FFFu + ((t.i >> 16) & 1u);   // RNE
    return (ushort_t)(r >> 16);
}
__device__ __forceinline__ uint_t cvt_pk_bf16(float a, float b) {
    uint_t r;
    asm("v_cvt_pk_bf16_f32 %0, %1, %2" : "=v"(r) : "v"(a), "v"(b));
    return r;
}

// 16x16x32: D[m][n] += sum_k A[m,k]*B[k,n]
// D-frag (HW-verified m89/m91): col=lane&15, row=(lane>>4)*4+reg.
__device__ __forceinline__ f32x4 mfma_bf16(s8v a, s8v b, f32x4 c) {
    asm volatile("v_mfma_f32_16x16x32_bf16 %0, %1, %2, %0" : "+v"(c) : "v"(a), "v"(b));
    return c;
}
// 32x32x16: D-frag (HW-verified m74/m101): col=lane&31, row=(reg&3)+8*(reg>>2)+4*(lane>>5)
__device__ __forceinline__ f32x16 mfma32_bf16(s8v a, s8v b, f32x16 c) {
    asm volatile("v_mfma_f32_32x32x16_bf16 %0, %1, %2, %0" : "+v"(c) : "v"(a), "v"(b));
    return c;
}

// async global->LDS, 16B per lane; LDS dest = wave-uniform base + lane*16.
__device__ __forceinline__ void gload16(const void* g, void* l) {
    __builtin_amdgcn_global_load_lds(
        (const __attribute__((address_space(1))) uint_t*)g,
        (__attribute__((address_space(3))) uint_t*)l, 16, 0, 0);
}

// ---------------------------------------------------------------------------
// fp32 -> bf16, 8 elements/thread
// ---------------------------------------------------------------------------
__global__ __launch_bounds__(256) void f32_to_bf16_vec(const float* __restrict__ src,
                                                       short* __restrict__ dst, int n8) {
    int i = blockIdx.x * 256 + threadIdx.x;
    if (i < n8) {
        float4 a = *(const float4*)(src + (size_t)i * 8);
        float4 b = *(const float4*)(src + (size_t)i * 8 + 4);
        s8v t;
        t[0] = (short)f2b(a.x); t[1] = (short)f2b(a.y);
        t[2] = (short)f2b(a.z); t[3] = (short)f2b(a.w);
        t[4] = (short)f2b(b.x); t[5] = (short)f2b(b.y);
        t[6] = (short)f2b(b.z); t[7] = (short)f2b(b.w);
        *(s8v*)(dst + (size_t)i * 8) = t;
    }
}

// ---------------------------------------------------------------------------
// RoPE cos/sin tables [S][HD] fp32
// ---------------------------------------------------------------------------
__global__ __launch_bounds__(256) void rope_tables(float* __restrict__ cos_t,
                                                   float* __restrict__ sin_t) {
    int idx = blockIdx.x * 256 + threadIdx.x;     // 0 .. 65535
    int s = idx >> 6;
    int d = idx & 63;
    int pos = (d < 32) ? (s >> 5) : (s & 31);
    int i   = (d & 31) >> 1;
    float freq  = expf(-(float)i * 0.5756462732485115f);   // ln(10000)/16
    float angle = (float)pos * 0.5f * freq;
    cos_t[idx] = cosf(angle);
    sin_t[idx] = sinf(angle);
}

// ---------------------------------------------------------------------------
// W[K][N] fp32 -> WT[N][K] bf16  (32x32 LDS tile transpose)
// ---------------------------------------------------------------------------
__global__ __launch_bounds__(256) void transpose_to_bf16(const float* __restrict__ Wsrc,
                                                         short* __restrict__ WT,
                                                         int K, int N) {
    __shared__ float t[32][33];
    int tx = threadIdx.x & 31, ty = threadIdx.x >> 5;   // ty 0..7
    int n0 = blockIdx.x * 32, k0 = blockIdx.y * 32;
#pragma unroll
    for (int i = 0; i < 4; ++i)
        t[ty + 8 * i][tx] = Wsrc[(size_t)(k0 + ty + 8 * i) * N + n0 + tx];
    __syncthreads();
#pragma unroll
    for (int i = 0; i < 4; ++i)
        WT[(size_t)(n0 + ty + 8 * i) * K + k0 + tx] = (short)f2b(t[tx][ty + 8 * i]);
}

// ---------------------------------------------------------------------------
// bf16 MFMA GEMM, m97 structure (round-5 version, known-good):
// 128x128 tile, BK=64, linear LDS, global_load_lds width-16, 4 waves,
// 4x4 frags/wave, 2 barriers/K-step. NORM: fused RMSNorm+RoPE epilogue.
// ---------------------------------------------------------------------------
template<typename CT, bool NORM>
__global__ __launch_bounds__(256) void gemm_glds(
        const short* __restrict__ A, const short* __restrict__ BT,
        const float* __restrict__ bias, CT* __restrict__ C,
        int M, int N, int K, int NX,
        const float* __restrict__ qw, const float* __restrict__ kw,
        const float* __restrict__ cos_t, const float* __restrict__ sin_t) {
    __shared__ short As[128 * 64];   // [row][k] linear, 16 KiB
    __shared__ short Bs[128 * 64];

    const int tid  = threadIdx.x;
    const int w    = tid >> 6;
    const int lane = tid & 63;
    const int l15  = lane & 15, lg = lane >> 4;

    const int nwg  = gridDim.x;
    const int cpx  = nwg >> 3;
    const int wgid = (blockIdx.x & 7) * cpx + (blockIdx.x >> 3);
    const int bx = wgid % NX, by = wgid / NX;
    const int m0 = by * 128, n0 = bx * 128;
    const int wr = (w >> 1) * 64, wc = (w & 1) * 64;

    const int srow = w * 32 + (lane >> 3);
    const int sk   = (lane & 7) * 8;

    f32x4 acc[4][4] = {};

    for (int k0 = 0; k0 < K; k0 += 64) {
        __syncthreads();
#pragma unroll
        for (int i = 0; i < 4; ++i) {
            int r = srow + i * 8;
            gload16(A  + (size_t)(m0 + r) * K + k0 + sk, &As[(w * 4 + i) * 512]);
            gload16(BT + (size_t)(n0 + r) * K + k0 + sk, &Bs[(w * 4 + i) * 512]);
        }
        __syncthreads();

#pragma unroll
        for (int kk = 0; kk < 2; ++kk) {
            s8v af[4], bf[4];
#pragma unroll
            for (int i = 0; i < 4; ++i) {
                af[i] = *(const s8v*)&As[(wr + 16 * i + l15) * 64 + kk * 32 + lg * 8];
                bf[i] = *(const s8v*)&Bs[(wc + 16 * i + l15) * 64 + kk * 32 + lg * 8];
            }
#pragma unroll
            for (int mi = 0; mi < 4; ++mi)
#pragma unroll
                for (int ni = 0; ni < 4; ++ni)
                    acc[mi][ni] = mfma_bf16(af[mi], bf[ni], acc[mi][ni]);
        }
    }

    if constexpr (NORM) {
        if (n0 + wc < 2048) {
            const float* nw = (n0 + wc < 1024) ? qw : kw;
            float wv[4], bv[4];
#pragma unroll
            for (int ni = 0; ni < 4; ++ni) {
                wv[ni] = nw[16 * ni + l15];
                bv[ni] = bias[n0 + wc + 16 * ni + l15];
            }
#pragma unroll
            for (int mi = 0; mi < 4; ++mi) {
#pragma unroll
                for (int r = 0; r < 4; ++r) {
                    int row = m0 + wr + 16 * mi + lg * 4 + r;
                    int s = row & (S_ - 1);
                    float v[4];
#pragma unroll
                    for (int ni = 0; ni < 4; ++ni) v[ni] = acc[mi][ni][r] + bv[ni];
                    float ss = v[0]*v[0] + v[1]*v[1] + v[2]*v[2] + v[3]*v[3];
                    ss += __shfl_xor(ss, 1);
                    ss += __shfl_xor(ss, 2);
                    ss += __shfl_xor(ss, 4);
                    ss += __shfl_xor(ss, 8);
                    float rms = rsqrtf(ss * (1.0f / 64.0f) + 1e-6f);
                    float xn[4];
#pragma unroll
                    for (int ni = 0; ni < 4; ++ni) xn[ni] = v[ni] * rms * wv[ni];
#pragma unroll
                    for (int ni = 0; ni < 4; ++ni) {
                        int d = 16 * ni + l15;
                        float c  = cos_t[s * 64 + d];
                        float sn = sin_t[s * 64 + d];
                        float rot = (ni < 2) ? -xn[ni + 2] : xn[ni - 2];
                        C[(size_t)row * N + n0 + wc + d] = (short)f2b(xn[ni] * c + rot * sn);
                    }
                }
            }
            return;
        }
    }
#pragma unroll
    for (int ni = 0; ni < 4; ++ni) {
        float bvv = bias[n0 + wc + 16 * ni + l15];
#pragma unroll
        for (int mi = 0; mi < 4; ++mi) {
#pragma unroll
            for (int r = 0; r < 4; ++r) {
                size_t row = (size_t)(m0 + wr + 16 * mi + lg * 4 + r);
                int    col = n0 + wc + 16 * ni + l15;
                float v = acc[mi][ni][r] + bvv;
                if constexpr (sizeof(CT) == 4) C[row * N + col] = v;
                else                           C[row * N + col] = (short)f2b(v);
            }
        }
    }
}

// ---------------------------------------------------------------------------
// MFMA flash attention, 32x32x16 dataflow (HK-style, T12):
//  - swapped QK^T with 32x32 MFMA: q is lane-local (col=lane&31), keys live in
//    16 regs + lane bit5 -> softmax is in-lane + ONE shfl_xor(32).
//  - P relayout for PV entirely in-register: cvt_pk pairs + shfl_xor(32) +
//    cndmask by lane bit5 (algebra from the verified D-layout).
//  - NO P LDS buffer: LDS = 18.4 KB (Ks + Vt only) -> 2x blocks/CU headroom.
//  - PV: O^T[d][q] = mfma(A=V^T from Vt, B=P). alpha & 1/l are lane-local.
//  - O transposed through the freed LDS pool for coalesced 16B stores.
// Grid 2048 (XCD-band remap), 256 thr = 4 waves; wave w: q rows [q0+32w,+32).
// ---------------------------------------------------------------------------
__global__ __launch_bounds__(256) void attn_mfma(const short* __restrict__ qkv,
                                                 short* __restrict__ attn) {
    __shared__ ushort_t pool[9216];            // 18 KiB: Ks[64][72] | Vt[64][72]
    ushort_t* Ks = pool;                       // [key][d], pitch 72
    ushort_t* Vt = pool + 4608;                // [d][key-swizzled], pitch 72

    const float SC  = 0.18033688011112042f;    // 0.125 * log2(e)
    const float THR = 11.0f;

    const int tid  = threadIdx.x;
    const int w    = tid >> 6;
    const int lane = tid & 63;
    const int l31  = lane & 31, l5 = lane >> 5;

    // XCD remap: bid -> (xcd, j); bh = xcd*32 + (j&31); qt = j>>5
    const int bid = blockIdx.x;
    const int xcd = bid & 7;
    const int jj_ = bid >> 3;
    const int bh  = xcd * 32 + (jj_ & 31);
    const int b   = bh >> 4, h = bh & 15;
    const int q0  = (jj_ >> 5) * 128;

    const short* qbase = qkv + (size_t)b * S_ * TDIM + h * HD_;
    const short* kb_ = qbase + DIM_;
    const short* vb_ = qbase + 2 * DIM_;

    // Q fragments: B-operand, n = q = lane&31, k-chunk kc: k = kc*16 + l5*8 + j
    s8v qf[4];
#pragma unroll
    for (int kc = 0; kc < 4; ++kc)
        qf[kc] = *(const s8v*)(qbase + (size_t)(q0 + w * 32 + l31) * TDIM + kc * 16 + l5 * 8);

    f32x16 of0 = {}, of1 = {};                 // O^T frags, d-blocks 0/1
    float m_s = -1e30f, l_s = 0.f;

    // staging geometry (unchanged)
    const int kr   = tid >> 3;
    const int kp8  = (tid & 7) * 8;
    const int vkp  = tid >> 3;
    const int va   = tid & 7;
    const int vp8  = va * 8;
    const int vcol = (2 * vkp) ^ ((va & 3) << 4);
    const int vsw  = ((l31 >> 3) & 3) << 4;    // Vt read-side swizzle (same for both d-blocks)

    s8v kA, kB, vA, vB;
    auto prefetch = [&](int kt) {
        const short* kbt = kb_ + (size_t)kt * 64 * TDIM;
        const short* vbt = vb_ + (size_t)kt * 64 * TDIM;
        kA = *(const s8v*)(kbt + (size_t)kr * TDIM + kp8);
        kB = *(const s8v*)(kbt + (size_t)(kr + 32) * TDIM + kp8);
        vA = *(const s8v*)(vbt + (size_t)(2 * vkp) * TDIM + vp8);
        vB = *(const s8v*)(vbt + (size_t)(2 * vkp + 1) * TDIM + vp8);
    };
    prefetch(0);

    for (int kt = 0; kt < 16; ++kt) {
        // write prefetched tile -> LDS
        *(s8v*)&Ks[kr * 72 + kp8]        = kA;
        *(s8v*)&Ks[(kr + 32) * 72 + kp8] = kB;
#pragma unroll
        for (int j = 0; j < 8; ++j) {
            uint_t pk = (ushort_t)vA[j] | ((uint_t)(ushort_t)vB[j] << 16);
            *(uint_t*)&Vt[(vp8 + j) * 72 + vcol] = pk;
        }
        __syncthreads();

        if (kt < 15) prefetch(kt + 1);   // overlap with compute

        // ---- QK^T (swapped): st{0,1} = S^T[key-block][q] 32x32 frags
        f32x16 st0 = {}, st1 = {};
        __builtin_amdgcn_s_setprio(1);
#pragma unroll
        for (int kc = 0; kc < 4; ++kc) {
            s8v kf0 = *(const s8v*)&Ks[l31 * 72 + kc * 16 + l5 * 8];
            s8v kf1 = *(const s8v*)&Ks[(32 + l31) * 72 + kc * 16 + l5 * 8];
            st0 = mfma32_bf16(kf0, qf[kc], st0);
            st1 = mfma32_bf16(kf1, qf[kc], st1);
        }
        __builtin_amdgcn_s_setprio(0);

        // ---- softmax: q = l31 is lane-local; keys = (r&3)+8(r>>2)+4*l5 (+32*kb)
        float mx = -1e30f;
#pragma unroll
        for (int r = 0; r < 16; ++r)
            mx = fmaxf(mx, fmaxf(st0[r], st1[r]));
        mx = fmaxf(mx, __shfl_xor(mx, 32));
        float mxs = mx * SC;

        if (!__all(mxs <= m_s + THR)) {          // wave-uniform
            float mnew  = fmaxf(m_s, mxs);
            float alpha = exp2f(m_s - mnew);     // lane-local, no shuffles
            m_s = mnew;
            l_s *= alpha;
#pragma unroll
            for (int r = 0; r < 16; ++r) { of0[r] *= alpha; of1[r] *= alpha; }
        }

        float ls = 0.f;
#pragma unroll
        for (int r = 0; r < 16; ++r) {
            float p0 = exp2f(__builtin_fmaf(st0[r], SC, -m_s));
            float p1 = exp2f(__builtin_fmaf(st1[r], SC, -m_s));
            st0[r] = p0; st1[r] = p1;
            ls += p0 + ls * 0.0f + p1;           // simple accumulate
        }
        ls += __shfl_xor(ls, 32);
        l_s += ls;

        // ---- P -> bf16 pairs (u32), per key-block: P2[i] = keys {8(i>>1)+4*l5+2(i&1), +1}
        uint_t P20[8], P21[8];
#pragma unroll
        for (int i = 0; i < 8; ++i) {
            P20[i] = cvt_pk_bf16(st0[2 * i], st0[2 * i + 1]);
            P21[i] = cvt_pk_bf16(st1[2 * i], st1[2 * i + 1]);
        }

        // ---- PV: O^T[d][q] += V^T[d][key] * P[key][q], key chunks of 16
#pragma unroll
        for (int kb = 0; kb < 2; ++kb) {
            const uint_t* P2 = kb ? P21 : P20;
#pragma unroll
            for (int c = 0; c < 2; ++c) {
                // exchange partner-half pair-words (lane bit5)
                uint_t sw0 = __shfl_xor((int)P2[4 * c + 0], 32);
                uint_t sw1 = __shfl_xor((int)P2[4 * c + 1], 32);
                uint_t sw2 = __shfl_xor((int)P2[4 * c + 2], 32);
                uint_t sw3 = __shfl_xor((int)P2[4 * c + 3], 32);
                union { uint_t u[4]; s8v v; } pf;
                pf.u[0] = l5 ? sw2           : P2[4 * c + 0];   // keys c16+l5*8+{0,1}
                pf.u[1] = l5 ? sw3           : P2[4 * c + 1];   // {2,3}
                pf.u[2] = l5 ? P2[4 * c + 2] : sw0;             // {4,5}
                pf.u[3] = l5 ? P2[4 * c + 3] : sw1;             // {6,7}

                int kcol = (kb * 32 + c * 16 + l5 * 8) ^ vsw;
                s8v vf0 = *(const s8v*)&Vt[l31 * 72 + kcol];
                s8v vf1 = *(const s8v*)&Vt[(32 + l31) * 72 + kcol];
                __builtin_amdgcn_s_setprio(1);
                of0 = mfma32_bf16(vf0, pf.v, of0);
                of1 = mfma32_bf16(vf1, pf.v, of1);
                __builtin_amdgcn_s_setprio(0);
            }
        }
        __syncthreads();
    }

    // ---- epilogue: O^T -> LDS transpose -> coalesced 16B stores
    float inv = 1.0f / l_s;
    ushort_t* OL = pool + w * 2304;        // per-wave [32 q][72], wave-private
#pragma unroll
    for (int r = 0; r < 16; ++r) {
        int d = (r & 3) + 8 * (r >> 2) + 4 * l5;
        OL[l31 * 72 + d]      = f2b(of0[r] * inv);
        OL[l31 * 72 + 32 + d] = f2b(of1[r] * inv);
    }
    // wave-private region: compiler orders LDS ops within the wave
#pragma unroll
    for (int i = 0; i < 4; ++i) {
        int idx = lane + i * 64;
        int row = idx >> 3, ch = idx & 7;
        *(s8v*)&attn[((size_t)b * S_ + q0 + w * 32 + row) * DIM_ + h * HD_ + ch * 8] =
            *(const s8v*)&OL[row * 72 + ch * 8];
    }
}

// ---------------------------------------------------------------------------
extern "C" void kernel_launch(void* const* d_in, const int* in_sizes, int n_in,
                              void* d_out, int out_size, void* d_ws, size_t ws_size,
                              hipStream_t stream) {
    const float* x        = (const float*)d_in[0];
    const float* w_qkv    = (const float*)d_in[1];
    const float* b_qkv    = (const float*)d_in[2];
    const float* q_norm_w = (const float*)d_in[3];
    const float* k_norm_w = (const float*)d_in[4];
    const float* w_out    = (const float*)d_in[5];
    const float* b_out    = (const float*)d_in[6];
    float* out = (float*)d_out;

    const size_t OFF_QKV = 0;                          //  96 MiB: qkv bf16
    const size_t OFF_ATT = 100663296;                  //  32 MiB: attn bf16
    const size_t OFF_XB  = OFF_ATT + 33554432;         //  32 MiB: x bf16
    const size_t OFF_WQ  = OFF_XB + 33554432;          //   6 MiB: w_qkv^T bf16
    const size_t OFF_WO  = OFF_WQ + 6291456;           //   2 MiB: w_out^T bf16
    const size_t OFF_CT  = OFF_WO + 2097152;           // 256 KiB: cos table
    const size_t OFF_ST  = OFF_CT + 262144;            // 256 KiB: sin table
    const size_t NEED    = OFF_ST + 262144;

    if (ws_size < NEED) {
        hipMemsetAsync(d_out, 0, (size_t)out_size * sizeof(float), stream);
        return;
    }

    char* ws = (char*)d_ws;
    short* qkv   = (short*)(ws + OFF_QKV);
    short* attnb = (short*)(ws + OFF_ATT);
    short* xb    = (short*)(ws + OFF_XB);
    short* wqkvT = (short*)(ws + OFF_WQ);
    short* woutT = (short*)(ws + OFF_WO);
    float* cos_t = (float*)(ws + OFF_CT);
    float* sin_t = (float*)(ws + OFF_ST);

    // 0: tables, conversions, weight transposes
    rope_tables<<<dim3(256), dim3(256), 0, stream>>>(cos_t, sin_t);
    f32_to_bf16_vec<<<dim3(8192), dim3(256), 0, stream>>>(x, xb, 2097152);
    transpose_to_bf16<<<dim3(96, 32), dim3(256), 0, stream>>>(w_qkv, wqkvT, 1024, 3072);
    transpose_to_bf16<<<dim3(32, 32), dim3(256), 0, stream>>>(w_out, woutT, 1024, 1024);

    // 1: qkv = x @ w_qkv + b_qkv, fused RMSNorm+RoPE epilogue on q,k columns.
    gemm_glds<short, true><<<dim3(3072), dim3(256), 0, stream>>>(
        xb, wqkvT, b_qkv, qkv, 16384, 3072, 1024, 24,
        q_norm_w, k_norm_w, cos_t, sin_t);

    // 2: flash attention -> attnb (bf16)
    attn_mfma<<<dim3(2048), dim3(256), 0, stream>>>(qkv, attnb);

    // 3: out = attn @ w_out + b_out (fp32 out)
    gemm_glds<float, false><<<dim3(1024), dim3(256), 0, stream>>>(
        attnb, woutT, b_out, out, 16384, 1024, 1024, 8,
        nullptr, nullptr, nullptr, nullptr);
}

// Round 9
// 319.755 us; speedup vs baseline: 1.1128x; 1.0832x over previous
//
#include <hip/hip_runtime.h>
#include <cstdint>
#include <cstddef>

#define B_    16
#define S_    1024
#define DIM_  1024
#define H_    16
#define HD_   64
#define TDIM  3072   // 3*DIM

typedef unsigned short ushort_t;
typedef unsigned int   uint_t;
typedef __attribute__((ext_vector_type(8)))  short s8v;    // 8 bf16 = 4 VGPRs
typedef __attribute__((ext_vector_type(4)))  float f32x4;
typedef __attribute__((ext_vector_type(16))) float f32x16;

__device__ __forceinline__ float b2f(ushort_t u) {
    union { uint_t i; float f; } t; t.i = (uint_t)u << 16; return t.f;
}
__device__ __forceinline__ ushort_t f2b(float f) {
    union { float f; uint_t i; } t; t.f = f;
    uint_t r = t.i + 0x7FFFu + ((t.i >> 16) & 1u);   // RNE
    return (ushort_t)(r >> 16);
}
__device__ __forceinline__ uint_t cvt_pk_bf16(float a, float b) {
    uint_t r;
    asm("v_cvt_pk_bf16_f32 %0, %1, %2" : "=v"(r) : "v"(a), "v"(b));
    return r;
}

// 16x16x32: D[m][n] += sum_k A[m,k]*B[k,n]
// D-frag (HW-verified m89/m91): col=lane&15, row=(lane>>4)*4+reg.
__device__ __forceinline__ f32x4 mfma_bf16(s8v a, s8v b, f32x4 c) {
    asm volatile("v_mfma_f32_16x16x32_bf16 %0, %1, %2, %0" : "+v"(c) : "v"(a), "v"(b));
    return c;
}
// 32x32x16: D-frag (HW-verified m74/m101): col=lane&31, row=(reg&3)+8*(reg>>2)+4*(lane>>5)
__device__ __forceinline__ f32x16 mfma32_bf16(s8v a, s8v b, f32x16 c) {
    asm volatile("v_mfma_f32_32x32x16_bf16 %0, %1, %2, %0" : "+v"(c) : "v"(a), "v"(b));
    return c;
}

// async global->LDS, 16B per lane; LDS dest = wave-uniform base + lane*16.
__device__ __forceinline__ void gload16(const void* g, void* l) {
    __builtin_amdgcn_global_load_lds(
        (const __attribute__((address_space(1))) uint_t*)g,
        (__attribute__((address_space(3))) uint_t*)l, 16, 0, 0);
}

// raw barrier (no compiler vmcnt drain) + explicit vm wait
__device__ __forceinline__ void bar() {
    asm volatile("" ::: "memory");
    __builtin_amdgcn_s_barrier();
    asm volatile("" ::: "memory");
}
__device__ __forceinline__ void wait_vm0() {
    asm volatile("s_waitcnt vmcnt(0)" ::: "memory");
}

// ---------------------------------------------------------------------------
// fp32 -> bf16, 8 elements/thread
// ---------------------------------------------------------------------------
__global__ __launch_bounds__(256) void f32_to_bf16_vec(const float* __restrict__ src,
                                                       short* __restrict__ dst, int n8) {
    int i = blockIdx.x * 256 + threadIdx.x;
    if (i < n8) {
        float4 a = *(const float4*)(src + (size_t)i * 8);
        float4 b = *(const float4*)(src + (size_t)i * 8 + 4);
        s8v t;
        t[0] = (short)f2b(a.x); t[1] = (short)f2b(a.y);
        t[2] = (short)f2b(a.z); t[3] = (short)f2b(a.w);
        t[4] = (short)f2b(b.x); t[5] = (short)f2b(b.y);
        t[6] = (short)f2b(b.z); t[7] = (short)f2b(b.w);
        *(s8v*)(dst + (size_t)i * 8) = t;
    }
}

// ---------------------------------------------------------------------------
// RoPE cos/sin tables [S][HD] fp32
// ---------------------------------------------------------------------------
__global__ __launch_bounds__(256) void rope_tables(float* __restrict__ cos_t,
                                                   float* __restrict__ sin_t) {
    int idx = blockIdx.x * 256 + threadIdx.x;     // 0 .. 65535
    int s = idx >> 6;
    int d = idx & 63;
    int pos = (d < 32) ? (s >> 5) : (s & 31);
    int i   = (d & 31) >> 1;
    float freq  = expf(-(float)i * 0.5756462732485115f);   // ln(10000)/16
    float angle = (float)pos * 0.5f * freq;
    cos_t[idx] = cosf(angle);
    sin_t[idx] = sinf(angle);
}

// ---------------------------------------------------------------------------
// W[K][N] fp32 -> WT[N][K] bf16  (32x32 LDS tile transpose)
// ---------------------------------------------------------------------------
__global__ __launch_bounds__(256) void transpose_to_bf16(const float* __restrict__ Wsrc,
                                                         short* __restrict__ WT,
                                                         int K, int N) {
    __shared__ float t[32][33];
    int tx = threadIdx.x & 31, ty = threadIdx.x >> 5;   // ty 0..7
    int n0 = blockIdx.x * 32, k0 = blockIdx.y * 32;
#pragma unroll
    for (int i = 0; i < 4; ++i)
        t[ty + 8 * i][tx] = Wsrc[(size_t)(k0 + ty + 8 * i) * N + n0 + tx];
    __syncthreads();
#pragma unroll
    for (int i = 0; i < 4; ++i)
        WT[(size_t)(n0 + ty + 8 * i) * K + k0 + tx] = (short)f2b(t[tx][ty + 8 * i]);
}

// ---------------------------------------------------------------------------
// 8-phase 256x256 bf16 MFMA GEMM (m201-style, T2+T3+T4+T5):
//   C[M,N] = A[M,K] @ B[K,N] + bias, B given as BT[N,K]. A,BT bf16.
//   512 thr = 8 waves (2M x 4N); per-wave output 128x64 = acc[8][4].
//   BK=64; LDS 128 KiB double-buffered, XOR-swizzled storage:
//     LDS slot (row, chunk c of 8 shorts) holds global k-chunk c^(row&7);
//     achieved with linear gload dest + inverse-swizzled GLOBAL source,
//     and swizzled ds_read addresses (rule #21: both sides, same involution).
//   Per K-tile: 4 phases {ds_read subtile; stage next tile; bar; 16 MFMA; bar}
//   with ONE vm-wait at the K-tile boundary (loads issued ph1/ph2 -> ~3
//   phases of latency cover; never a mid-phase drain).
//   NORM: fused per-head RMSNorm + RoPE epilogue for columns < 2048 (q,k).
// ---------------------------------------------------------------------------
template<typename CT, bool NORM>
__global__ __launch_bounds__(512, 2) void gemm8ph(
        const short* __restrict__ A, const short* __restrict__ BT,
        const float* __restrict__ bias, CT* __restrict__ C,
        int M, int N, int K, int NX,
        const float* __restrict__ qw, const float* __restrict__ kw,
        const float* __restrict__ cos_t, const float* __restrict__ sin_t) {
    __shared__ short As[2][256 * 64];   // 64 KiB  [buf][row*64 + swizzled col]
    __shared__ short Bs[2][256 * 64];   // 64 KiB

    const int tid  = threadIdx.x;
    const int w    = tid >> 6;           // 0..7
    const int lane = tid & 63;
    const int l15  = lane & 15, lg = lane >> 4;
    const int wm = w >> 2, wn = w & 3;   // wave grid 2(M) x 4(N)

    // bijective XCD-chunked remap (nwg % 8 == 0)
    const int nwg  = gridDim.x;
    const int cpx  = nwg >> 3;
    const int wgid = (blockIdx.x & 7) * cpx + (blockIdx.x >> 3);
    const int bx = wgid % NX, by = wgid / NX;
    const int m0 = by * 256, n0 = bx * 256;

    const int NT = K >> 6;               // K-tiles of 64

    // staging: instr j covers rows j*64 + w*8 + (lane>>3); global k-chunk is
    // inverse-swizzled so that LDS slot chunk (lane&7) holds global chunk
    // (lane&7)^(row&7); row&7 == lane>>3 here.
    const int sgrow = w * 8 + (lane >> 3);            // + j*64
    const int ksrc  = (((lane & 7) ^ (lane >> 3)) * 8);

    auto stageA = [&](int t, int buf) {
        const size_t k0 = (size_t)t * 64;
#pragma unroll
        for (int j = 0; j < 4; ++j)
            gload16(A + (size_t)(m0 + j * 64 + sgrow) * K + k0 + ksrc,
                    &As[buf][(j * 64 + w * 8) * 64]);
    };
    auto stageB = [&](int t, int buf) {
        const size_t k0 = (size_t)t * 64;
#pragma unroll
        for (int j = 0; j < 4; ++j)
            gload16(BT + (size_t)(n0 + j * 64 + sgrow) * K + k0 + ksrc,
                    &Bs[buf][(j * 64 + w * 8) * 64]);
    };

    // prologue: stage tile 0 into buf 0, drain, barrier
    stageA(0, 0);
    stageB(0, 0);
    wait_vm0();
    bar();

    f32x4 acc[8][4] = {};
    s8v a_f[4][2];   // current mh's A frags [i][kk]
    s8v b_f[4][2];   // all 4 ni B frags [ni][kk], loaded ph1+ph2

    const int swz = l15 & 7;   // read-side chunk swizzle

    for (int t = 0; t < NT; ++t) {
        const int buf = t & 1;
        const bool more = (t + 1 < NT);

        // ---- phase 1: read A-mh0 (8) + B-nh0 (4); stage next A; MFMA (mh0,nh0)
#pragma unroll
        for (int i = 0; i < 4; ++i) {
            int row = wm * 128 + i * 16 + l15;
#pragma unroll
            for (int kk = 0; kk < 2; ++kk)
                a_f[i][kk] = *(const s8v*)&As[buf][row * 64 + (((kk * 4 + lg) ^ swz) * 8)];
        }
#pragma unroll
        for (int ni = 0; ni < 2; ++ni) {
            int row = wn * 64 + ni * 16 + l15;
#pragma unroll
            for (int kk = 0; kk < 2; ++kk)
                b_f[ni][kk] = *(const s8v*)&Bs[buf][row * 64 + (((kk * 4 + lg) ^ swz) * 8)];
        }
        if (more) stageA(t + 1, buf ^ 1);
        bar();
        __builtin_amdgcn_s_setprio(1);
#pragma unroll
        for (int i = 0; i < 4; ++i)
#pragma unroll
            for (int ni = 0; ni < 2; ++ni)
#pragma unroll
                for (int kk = 0; kk < 2; ++kk)
                    acc[i][ni] = mfma_bf16(a_f[i][kk], b_f[ni][kk], acc[i][ni]);
        __builtin_amdgcn_s_setprio(0);
        bar();

        // ---- phase 2: read B-nh1 (4); stage next B; MFMA (mh0,nh1)
#pragma unroll
        for (int ni = 2; ni < 4; ++ni) {
            int row = wn * 64 + ni * 16 + l15;
#pragma unroll
            for (int kk = 0; kk < 2; ++kk)
                b_f[ni][kk] = *(const s8v*)&Bs[buf][row * 64 + (((kk * 4 + lg) ^ swz) * 8)];
        }
        if (more) stageB(t + 1, buf ^ 1);
        bar();
        __builtin_amdgcn_s_setprio(1);
#pragma unroll
        for (int i = 0; i < 4; ++i)
#pragma unroll
            for (int ni = 2; ni < 4; ++ni)
#pragma unroll
                for (int kk = 0; kk < 2; ++kk)
                    acc[i][ni] = mfma_bf16(a_f[i][kk], b_f[ni][kk], acc[i][ni]);
        __builtin_amdgcn_s_setprio(0);
        bar();

        // ---- phase 3: read A-mh1 (8, reuse regs); MFMA (mh1,nh0)
#pragma unroll
        for (int i = 0; i < 4; ++i) {
            int row = wm * 128 + 64 + i * 16 + l15;
#pragma unroll
            for (int kk = 0; kk < 2; ++kk)
                a_f[i][kk] = *(const s8v*)&As[buf][row * 64 + (((kk * 4 + lg) ^ swz) * 8)];
        }
        bar();
        __builtin_amdgcn_s_setprio(1);
#pragma unroll
        for (int i = 0; i < 4; ++i)
#pragma unroll
            for (int ni = 0; ni < 2; ++ni)
#pragma unroll
                for (int kk = 0; kk < 2; ++kk)
                    acc[4 + i][ni] = mfma_bf16(a_f[i][kk], b_f[ni][kk], acc[4 + i][ni]);
        __builtin_amdgcn_s_setprio(0);
        bar();

        // ---- phase 4: MFMA (mh1,nh1); K-tile boundary: own-vm wait + barrier
        __builtin_amdgcn_s_setprio(1);
#pragma unroll
        for (int i = 0; i < 4; ++i)
#pragma unroll
            for (int ni = 2; ni < 4; ++ni)
#pragma unroll
                for (int kk = 0; kk < 2; ++kk)
                    acc[4 + i][ni] = mfma_bf16(a_f[i][kk], b_f[ni][kk], acc[4 + i][ni]);
        __builtin_amdgcn_s_setprio(0);
        wait_vm0();   // tile t+1 loads (issued ph1/ph2) - ~3 phases of cover
        bar();
    }

    // ---------------- epilogue ----------------
    const int colbase = n0 + wn * 64;
    if constexpr (NORM) {
        if (colbase < 2048) {
            const float* nw = (colbase < 1024) ? qw : kw;
            float wv[4], bv[4];
#pragma unroll
            for (int ni = 0; ni < 4; ++ni) {
                wv[ni] = nw[16 * ni + l15];
                bv[ni] = bias[colbase + 16 * ni + l15];
            }
#pragma unroll
            for (int mi = 0; mi < 8; ++mi) {
#pragma unroll
                for (int r = 0; r < 4; ++r) {
                    int row = m0 + wm * 128 + mi * 16 + lg * 4 + r;
                    int s = row & (S_ - 1);
                    float v[4];
#pragma unroll
                    for (int ni = 0; ni < 4; ++ni) v[ni] = acc[mi][ni][r] + bv[ni];
                    float ss = v[0]*v[0] + v[1]*v[1] + v[2]*v[2] + v[3]*v[3];
                    ss += __shfl_xor(ss, 1);
                    ss += __shfl_xor(ss, 2);
                    ss += __shfl_xor(ss, 4);
                    ss += __shfl_xor(ss, 8);
                    float rms = rsqrtf(ss * (1.0f / 64.0f) + 1e-6f);
                    float xn[4];
#pragma unroll
                    for (int ni = 0; ni < 4; ++ni) xn[ni] = v[ni] * rms * wv[ni];
#pragma unroll
                    for (int ni = 0; ni < 4; ++ni) {
                        int d = 16 * ni + l15;
                        float c  = cos_t[s * 64 + d];
                        float sn = sin_t[s * 64 + d];
                        float rot = (ni < 2) ? -xn[ni + 2] : xn[ni - 2];
                        C[(size_t)row * N + colbase + d] = (short)f2b(xn[ni] * c + rot * sn);
                    }
                }
            }
            return;
        }
    }
#pragma unroll
    for (int ni = 0; ni < 4; ++ni) {
        float bvv = bias[colbase + 16 * ni + l15];
#pragma unroll
        for (int mi = 0; mi < 8; ++mi) {
#pragma unroll
            for (int r = 0; r < 4; ++r) {
                size_t row = (size_t)(m0 + wm * 128 + mi * 16 + lg * 4 + r);
                int    col = colbase + 16 * ni + l15;
                float v = acc[mi][ni][r] + bvv;
                if constexpr (sizeof(CT) == 4) C[row * N + col] = v;
                else                           C[row * N + col] = (short)f2b(v);
            }
        }
    }
}

// ---------------------------------------------------------------------------
// MFMA flash attention, 32x32x16 dataflow (round-8 version, unchanged).
// ---------------------------------------------------------------------------
__global__ __launch_bounds__(256) void attn_mfma(const short* __restrict__ qkv,
                                                 short* __restrict__ attn) {
    __shared__ ushort_t pool[9216];            // 18 KiB: Ks[64][72] | Vt[64][72]
    ushort_t* Ks = pool;                       // [key][d], pitch 72
    ushort_t* Vt = pool + 4608;                // [d][key-swizzled], pitch 72

    const float SC  = 0.18033688011112042f;    // 0.125 * log2(e)
    const float THR = 11.0f;

    const int tid  = threadIdx.x;
    const int w    = tid >> 6;
    const int lane = tid & 63;
    const int l31  = lane & 31, l5 = lane >> 5;

    const int bid = blockIdx.x;
    const int xcd = bid & 7;
    const int jj_ = bid >> 3;
    const int bh  = xcd * 32 + (jj_ & 31);
    const int b   = bh >> 4, h = bh & 15;
    const int q0  = (jj_ >> 5) * 128;

    const short* qbase = qkv + (size_t)b * S_ * TDIM + h * HD_;
    const short* kb_ = qbase + DIM_;
    const short* vb_ = qbase + 2 * DIM_;

    s8v qf[4];
#pragma unroll
    for (int kc = 0; kc < 4; ++kc)
        qf[kc] = *(const s8v*)(qbase + (size_t)(q0 + w * 32 + l31) * TDIM + kc * 16 + l5 * 8);

    f32x16 of0 = {}, of1 = {};
    float m_s = -1e30f, l_s = 0.f;

    const int kr   = tid >> 3;
    const int kp8  = (tid & 7) * 8;
    const int vkp  = tid >> 3;
    const int va   = tid & 7;
    const int vp8  = va * 8;
    const int vcol = (2 * vkp) ^ ((va & 3) << 4);
    const int vsw  = ((l31 >> 3) & 3) << 4;

    s8v kA, kB, vA, vB;
    auto prefetch = [&](int kt) {
        const short* kbt = kb_ + (size_t)kt * 64 * TDIM;
        const short* vbt = vb_ + (size_t)kt * 64 * TDIM;
        kA = *(const s8v*)(kbt + (size_t)kr * TDIM + kp8);
        kB = *(const s8v*)(kbt + (size_t)(kr + 32) * TDIM + kp8);
        vA = *(const s8v*)(vbt + (size_t)(2 * vkp) * TDIM + vp8);
        vB = *(const s8v*)(vbt + (size_t)(2 * vkp + 1) * TDIM + vp8);
    };
    prefetch(0);

    for (int kt = 0; kt < 16; ++kt) {
        *(s8v*)&Ks[kr * 72 + kp8]        = kA;
        *(s8v*)&Ks[(kr + 32) * 72 + kp8] = kB;
#pragma unroll
        for (int j = 0; j < 8; ++j) {
            uint_t pk = (ushort_t)vA[j] | ((uint_t)(ushort_t)vB[j] << 16);
            *(uint_t*)&Vt[(vp8 + j) * 72 + vcol] = pk;
        }
        __syncthreads();

        if (kt < 15) prefetch(kt + 1);

        f32x16 st0 = {}, st1 = {};
        __builtin_amdgcn_s_setprio(1);
#pragma unroll
        for (int kc = 0; kc < 4; ++kc) {
            s8v kf0 = *(const s8v*)&Ks[l31 * 72 + kc * 16 + l5 * 8];
            s8v kf1 = *(const s8v*)&Ks[(32 + l31) * 72 + kc * 16 + l5 * 8];
            st0 = mfma32_bf16(kf0, qf[kc], st0);
            st1 = mfma32_bf16(kf1, qf[kc], st1);
        }
        __builtin_amdgcn_s_setprio(0);

        float mx = -1e30f;
#pragma unroll
        for (int r = 0; r < 16; ++r)
            mx = fmaxf(mx, fmaxf(st0[r], st1[r]));
        mx = fmaxf(mx, __shfl_xor(mx, 32));
        float mxs = mx * SC;

        if (!__all(mxs <= m_s + THR)) {
            float mnew  = fmaxf(m_s, mxs);
            float alpha = exp2f(m_s - mnew);
            m_s = mnew;
            l_s *= alpha;
#pragma unroll
            for (int r = 0; r < 16; ++r) { of0[r] *= alpha; of1[r] *= alpha; }
        }

        float ls = 0.f;
#pragma unroll
        for (int r = 0; r < 16; ++r) {
            float p0 = exp2f(__builtin_fmaf(st0[r], SC, -m_s));
            float p1 = exp2f(__builtin_fmaf(st1[r], SC, -m_s));
            st0[r] = p0; st1[r] = p1;
            ls += p0 + p1;
        }
        ls += __shfl_xor(ls, 32);
        l_s += ls;

        uint_t P20[8], P21[8];
#pragma unroll
        for (int i = 0; i < 8; ++i) {
            P20[i] = cvt_pk_bf16(st0[2 * i], st0[2 * i + 1]);
            P21[i] = cvt_pk_bf16(st1[2 * i], st1[2 * i + 1]);
        }

#pragma unroll
        for (int kb = 0; kb < 2; ++kb) {
            const uint_t* P2 = kb ? P21 : P20;
#pragma unroll
            for (int c = 0; c < 2; ++c) {
                uint_t sw0 = __shfl_xor((int)P2[4 * c + 0], 32);
                uint_t sw1 = __shfl_xor((int)P2[4 * c + 1], 32);
                uint_t sw2 = __shfl_xor((int)P2[4 * c + 2], 32);
                uint_t sw3 = __shfl_xor((int)P2[4 * c + 3], 32);
                union { uint_t u[4]; s8v v; } pf;
                pf.u[0] = l5 ? sw2           : P2[4 * c + 0];
                pf.u[1] = l5 ? sw3           : P2[4 * c + 1];
                pf.u[2] = l5 ? P2[4 * c + 2] : sw0;
                pf.u[3] = l5 ? P2[4 * c + 3] : sw1;

                int kcol = (kb * 32 + c * 16 + l5 * 8) ^ vsw;
                s8v vf0 = *(const s8v*)&Vt[l31 * 72 + kcol];
                s8v vf1 = *(const s8v*)&Vt[(32 + l31) * 72 + kcol];
                __builtin_amdgcn_s_setprio(1);
                of0 = mfma32_bf16(vf0, pf.v, of0);
                of1 = mfma32_bf16(vf1, pf.v, of1);
                __builtin_amdgcn_s_setprio(0);
            }
        }
        __syncthreads();
    }

    float inv = 1.0f / l_s;
    ushort_t* OL = pool + w * 2304;
#pragma unroll
    for (int r = 0; r < 16; ++r) {
        int d = (r & 3) + 8 * (r >> 2) + 4 * l5;
        OL[l31 * 72 + d]      = f2b(of0[r] * inv);
        OL[l31 * 72 + 32 + d] = f2b(of1[r] * inv);
    }
#pragma unroll
    for (int i = 0; i < 4; ++i) {
        int idx = lane + i * 64;
        int row = idx >> 3, ch = idx & 7;
        *(s8v*)&attn[((size_t)b * S_ + q0 + w * 32 + row) * DIM_ + h * HD_ + ch * 8] =
            *(const s8v*)&OL[row * 72 + ch * 8];
    }
}

// ---------------------------------------------------------------------------
extern "C" void kernel_launch(void* const* d_in, const int* in_sizes, int n_in,
                              void* d_out, int out_size, void* d_ws, size_t ws_size,
                              hipStream_t stream) {
    const float* x        = (const float*)d_in[0];
    const float* w_qkv    = (const float*)d_in[1];
    const float* b_qkv    = (const float*)d_in[2];
    const float* q_norm_w = (const float*)d_in[3];
    const float* k_norm_w = (const float*)d_in[4];
    const float* w_out    = (const float*)d_in[5];
    const float* b_out    = (const float*)d_in[6];
    float* out = (float*)d_out;

    const size_t OFF_QKV = 0;                          //  96 MiB: qkv bf16
    const size_t OFF_ATT = 100663296;                  //  32 MiB: attn bf16
    const size_t OFF_XB  = OFF_ATT + 33554432;         //  32 MiB: x bf16
    const size_t OFF_WQ  = OFF_XB + 33554432;          //   6 MiB: w_qkv^T bf16
    const size_t OFF_WO  = OFF_WQ + 6291456;           //   2 MiB: w_out^T bf16
    const size_t OFF_CT  = OFF_WO + 2097152;           // 256 KiB: cos table
    const size_t OFF_ST  = OFF_CT + 262144;            // 256 KiB: sin table
    const size_t NEED    = OFF_ST + 262144;

    if (ws_size < NEED) {
        hipMemsetAsync(d_out, 0, (size_t)out_size * sizeof(float), stream);
        return;
    }

    char* ws = (char*)d_ws;
    short* qkv   = (short*)(ws + OFF_QKV);
    short* attnb = (short*)(ws + OFF_ATT);
    short* xb    = (short*)(ws + OFF_XB);
    short* wqkvT = (short*)(ws + OFF_WQ);
    short* woutT = (short*)(ws + OFF_WO);
    float* cos_t = (float*)(ws + OFF_CT);
    float* sin_t = (float*)(ws + OFF_ST);

    // 0: tables, conversions, weight transposes
    rope_tables<<<dim3(256), dim3(256), 0, stream>>>(cos_t, sin_t);
    f32_to_bf16_vec<<<dim3(8192), dim3(256), 0, stream>>>(x, xb, 2097152);
    transpose_to_bf16<<<dim3(96, 32), dim3(256), 0, stream>>>(w_qkv, wqkvT, 1024, 3072);
    transpose_to_bf16<<<dim3(32, 32), dim3(256), 0, stream>>>(w_out, woutT, 1024, 1024);

    // 1: qkv = x @ w_qkv + b_qkv, fused RMSNorm+RoPE epilogue on q,k columns.
    //    grid = (16384/256)*(3072/256) = 64*12 = 768 (%8==0), 512 thr.
    gemm8ph<short, true><<<dim3(768), dim3(512), 0, stream>>>(
        xb, wqkvT, b_qkv, qkv, 16384, 3072, 1024, 12,
        q_norm_w, k_norm_w, cos_t, sin_t);

    // 2: flash attention -> attnb (bf16)
    attn_mfma<<<dim3(2048), dim3(256), 0, stream>>>(qkv, attnb);

    // 3: out = attn @ w_out + b_out (fp32 out); grid = 64*4 = 256
    gemm8ph<float, false><<<dim3(256), dim3(512), 0, stream>>>(
        attnb, woutT, b_out, out, 16384, 1024, 1024, 4,
        nullptr, nullptr, nullptr, nullptr);
}

// Round 11
// 318.513 us; speedup vs baseline: 1.1172x; 1.0039x over previous
//
#include <hip/hip_runtime.h>
#include <cstdint>
#include <cstddef>

#define B_    16
#define S_    1024
#define DIM_  1024
#define H_    16
#define HD_   64
#define TDIM  3072   // 3*DIM

typedef unsigned short ushort_t;
typedef unsigned int   uint_t;
typedef __attribute__((ext_vector_type(8)))  short s8v;    // 8 bf16 = 4 VGPRs
typedef __attribute__((ext_vector_type(4)))  float f32x4;
typedef __attribute__((ext_vector_type(16))) float f32x16;

__device__ __forceinline__ float b2f(ushort_t u) {
    union { uint_t i; float f; } t; t.i = (uint_t)u << 16; return t.f;
}
__device__ __forceinline__ ushort_t f2b(float f) {
    union { float f; uint_t i; } t; t.f = f;
    uint_t r = t.i + 0x7FFFu + ((t.i >> 16) & 1u);   // RNE
    return (ushort_t)(r >> 16);
}
__device__ __forceinline__ uint_t cvt_pk_bf16(float a, float b) {
    uint_t r;
    asm("v_cvt_pk_bf16_f32 %0, %1, %2" : "=v"(r) : "v"(a), "v"(b));
    return r;
}
__device__ __forceinline__ float max3f(float a, float b, float c) {
    float r;
    asm("v_max3_f32 %0, %1, %2, %3" : "=v"(r) : "v"(a), "v"(b), "v"(c));
    return r;
}

// 16x16x32: D[m][n] += sum_k A[m,k]*B[k,n]
// D-frag (HW-verified m89/m91): col=lane&15, row=(lane>>4)*4+reg.
__device__ __forceinline__ f32x4 mfma_bf16(s8v a, s8v b, f32x4 c) {
    asm volatile("v_mfma_f32_16x16x32_bf16 %0, %1, %2, %0" : "+v"(c) : "v"(a), "v"(b));
    return c;
}
// 32x32x16: D-frag (HW-verified m74/m101): col=lane&31, row=(reg&3)+8*(reg>>2)+4*(lane>>5)
__device__ __forceinline__ f32x16 mfma32_bf16(s8v a, s8v b, f32x16 c) {
    asm volatile("v_mfma_f32_32x32x16_bf16 %0, %1, %2, %0" : "+v"(c) : "v"(a), "v"(b));
    return c;
}

// async global->LDS, 16B per lane; LDS dest = wave-uniform base + lane*16.
__device__ __forceinline__ void gload16(const void* g, void* l) {
    __builtin_amdgcn_global_load_lds(
        (const __attribute__((address_space(1))) uint_t*)g,
        (__attribute__((address_space(3))) uint_t*)l, 16, 0, 0);
}

// raw barrier (no compiler vmcnt drain) + explicit vm wait
__device__ __forceinline__ void bar() {
    asm volatile("" ::: "memory");
    __builtin_amdgcn_s_barrier();
    asm volatile("" ::: "memory");
}
__device__ __forceinline__ void wait_vm0() {
    asm volatile("s_waitcnt vmcnt(0)" ::: "memory");
}

// ---------------------------------------------------------------------------
// fp32 -> bf16, 8 elements/thread
// ---------------------------------------------------------------------------
__global__ __launch_bounds__(256) void f32_to_bf16_vec(const float* __restrict__ src,
                                                       short* __restrict__ dst, int n8) {
    int i = blockIdx.x * 256 + threadIdx.x;
    if (i < n8) {
        float4 a = *(const float4*)(src + (size_t)i * 8);
        float4 b = *(const float4*)(src + (size_t)i * 8 + 4);
        s8v t;
        t[0] = (short)f2b(a.x); t[1] = (short)f2b(a.y);
        t[2] = (short)f2b(a.z); t[3] = (short)f2b(a.w);
        t[4] = (short)f2b(b.x); t[5] = (short)f2b(b.y);
        t[6] = (short)f2b(b.z); t[7] = (short)f2b(b.w);
        *(s8v*)(dst + (size_t)i * 8) = t;
    }
}

// ---------------------------------------------------------------------------
// RoPE cos/sin tables [S][HD] fp32
// ---------------------------------------------------------------------------
__global__ __launch_bounds__(256) void rope_tables(float* __restrict__ cos_t,
                                                   float* __restrict__ sin_t) {
    int idx = blockIdx.x * 256 + threadIdx.x;     // 0 .. 65535
    int s = idx >> 6;
    int d = idx & 63;
    int pos = (d < 32) ? (s >> 5) : (s & 31);
    int i   = (d & 31) >> 1;
    float freq  = expf(-(float)i * 0.5756462732485115f);   // ln(10000)/16
    float angle = (float)pos * 0.5f * freq;
    cos_t[idx] = cosf(angle);
    sin_t[idx] = sinf(angle);
}

// ---------------------------------------------------------------------------
// W[K][N] fp32 -> WT[N][K] bf16  (32x32 LDS tile transpose)
// ---------------------------------------------------------------------------
__global__ __launch_bounds__(256) void transpose_to_bf16(const float* __restrict__ Wsrc,
                                                         short* __restrict__ WT,
                                                         int K, int N) {
    __shared__ float t[32][33];
    int tx = threadIdx.x & 31, ty = threadIdx.x >> 5;   // ty 0..7
    int n0 = blockIdx.x * 32, k0 = blockIdx.y * 32;
#pragma unroll
    for (int i = 0; i < 4; ++i)
        t[ty + 8 * i][tx] = Wsrc[(size_t)(k0 + ty + 8 * i) * N + n0 + tx];
    __syncthreads();
#pragma unroll
    for (int i = 0; i < 4; ++i)
        WT[(size_t)(n0 + ty + 8 * i) * K + k0 + tx] = (short)f2b(t[tx][ty + 8 * i]);
}

// ---------------------------------------------------------------------------
// 8-phase 256x256 bf16 MFMA GEMM (round-9 version, unchanged — it works).
// ---------------------------------------------------------------------------
template<typename CT, bool NORM>
__global__ __launch_bounds__(512, 2) void gemm8ph(
        const short* __restrict__ A, const short* __restrict__ BT,
        const float* __restrict__ bias, CT* __restrict__ C,
        int M, int N, int K, int NX,
        const float* __restrict__ qw, const float* __restrict__ kw,
        const float* __restrict__ cos_t, const float* __restrict__ sin_t) {
    __shared__ short As[2][256 * 64];   // 64 KiB  [buf][row*64 + swizzled col]
    __shared__ short Bs[2][256 * 64];   // 64 KiB

    const int tid  = threadIdx.x;
    const int w    = tid >> 6;           // 0..7
    const int lane = tid & 63;
    const int l15  = lane & 15, lg = lane >> 4;
    const int wm = w >> 2, wn = w & 3;   // wave grid 2(M) x 4(N)

    const int nwg  = gridDim.x;
    const int cpx  = nwg >> 3;
    const int wgid = (blockIdx.x & 7) * cpx + (blockIdx.x >> 3);
    const int bx = wgid % NX, by = wgid / NX;
    const int m0 = by * 256, n0 = bx * 256;

    const int NT = K >> 6;               // K-tiles of 64

    const int sgrow = w * 8 + (lane >> 3);            // + j*64
    const int ksrc  = (((lane & 7) ^ (lane >> 3)) * 8);

    auto stageA = [&](int t, int buf) {
        const size_t k0 = (size_t)t * 64;
#pragma unroll
        for (int j = 0; j < 4; ++j)
            gload16(A + (size_t)(m0 + j * 64 + sgrow) * K + k0 + ksrc,
                    &As[buf][(j * 64 + w * 8) * 64]);
    };
    auto stageB = [&](int t, int buf) {
        const size_t k0 = (size_t)t * 64;
#pragma unroll
        for (int j = 0; j < 4; ++j)
            gload16(BT + (size_t)(n0 + j * 64 + sgrow) * K + k0 + ksrc,
                    &Bs[buf][(j * 64 + w * 8) * 64]);
    };

    stageA(0, 0);
    stageB(0, 0);
    wait_vm0();
    bar();

    f32x4 acc[8][4] = {};
    s8v a_f[4][2];
    s8v b_f[4][2];

    const int swz = l15 & 7;

    for (int t = 0; t < NT; ++t) {
        const int buf = t & 1;
        const bool more = (t + 1 < NT);

        // ---- phase 1
#pragma unroll
        for (int i = 0; i < 4; ++i) {
            int row = wm * 128 + i * 16 + l15;
#pragma unroll
            for (int kk = 0; kk < 2; ++kk)
                a_f[i][kk] = *(const s8v*)&As[buf][row * 64 + (((kk * 4 + lg) ^ swz) * 8)];
        }
#pragma unroll
        for (int ni = 0; ni < 2; ++ni) {
            int row = wn * 64 + ni * 16 + l15;
#pragma unroll
            for (int kk = 0; kk < 2; ++kk)
                b_f[ni][kk] = *(const s8v*)&Bs[buf][row * 64 + (((kk * 4 + lg) ^ swz) * 8)];
        }
        if (more) stageA(t + 1, buf ^ 1);
        bar();
        __builtin_amdgcn_s_setprio(1);
#pragma unroll
        for (int i = 0; i < 4; ++i)
#pragma unroll
            for (int ni = 0; ni < 2; ++ni)
#pragma unroll
                for (int kk = 0; kk < 2; ++kk)
                    acc[i][ni] = mfma_bf16(a_f[i][kk], b_f[ni][kk], acc[i][ni]);
        __builtin_amdgcn_s_setprio(0);
        bar();

        // ---- phase 2
#pragma unroll
        for (int ni = 2; ni < 4; ++ni) {
            int row = wn * 64 + ni * 16 + l15;
#pragma unroll
            for (int kk = 0; kk < 2; ++kk)
                b_f[ni][kk] = *(const s8v*)&Bs[buf][row * 64 + (((kk * 4 + lg) ^ swz) * 8)];
        }
        if (more) stageB(t + 1, buf ^ 1);
        bar();
        __builtin_amdgcn_s_setprio(1);
#pragma unroll
        for (int i = 0; i < 4; ++i)
#pragma unroll
            for (int ni = 2; ni < 4; ++ni)
#pragma unroll
                for (int kk = 0; kk < 2; ++kk)
                    acc[i][ni] = mfma_bf16(a_f[i][kk], b_f[ni][kk], acc[i][ni]);
        __builtin_amdgcn_s_setprio(0);
        bar();

        // ---- phase 3
#pragma unroll
        for (int i = 0; i < 4; ++i) {
            int row = wm * 128 + 64 + i * 16 + l15;
#pragma unroll
            for (int kk = 0; kk < 2; ++kk)
                a_f[i][kk] = *(const s8v*)&As[buf][row * 64 + (((kk * 4 + lg) ^ swz) * 8)];
        }
        bar();
        __builtin_amdgcn_s_setprio(1);
#pragma unroll
        for (int i = 0; i < 4; ++i)
#pragma unroll
            for (int ni = 0; ni < 2; ++ni)
#pragma unroll
                for (int kk = 0; kk < 2; ++kk)
                    acc[4 + i][ni] = mfma_bf16(a_f[i][kk], b_f[ni][kk], acc[4 + i][ni]);
        __builtin_amdgcn_s_setprio(0);
        bar();

        // ---- phase 4
        __builtin_amdgcn_s_setprio(1);
#pragma unroll
        for (int i = 0; i < 4; ++i)
#pragma unroll
            for (int ni = 2; ni < 4; ++ni)
#pragma unroll
                for (int kk = 0; kk < 2; ++kk)
                    acc[4 + i][ni] = mfma_bf16(a_f[i][kk], b_f[ni][kk], acc[4 + i][ni]);
        __builtin_amdgcn_s_setprio(0);
        wait_vm0();
        bar();
    }

    // ---------------- epilogue ----------------
    const int colbase = n0 + wn * 64;
    if constexpr (NORM) {
        if (colbase < 2048) {
            const float* nw = (colbase < 1024) ? qw : kw;
            float wv[4], bv[4];
#pragma unroll
            for (int ni = 0; ni < 4; ++ni) {
                wv[ni] = nw[16 * ni + l15];
                bv[ni] = bias[colbase + 16 * ni + l15];
            }
#pragma unroll
            for (int mi = 0; mi < 8; ++mi) {
#pragma unroll
                for (int r = 0; r < 4; ++r) {
                    int row = m0 + wm * 128 + mi * 16 + lg * 4 + r;
                    int s = row & (S_ - 1);
                    float v[4];
#pragma unroll
                    for (int ni = 0; ni < 4; ++ni) v[ni] = acc[mi][ni][r] + bv[ni];
                    float ss = v[0]*v[0] + v[1]*v[1] + v[2]*v[2] + v[3]*v[3];
                    ss += __shfl_xor(ss, 1);
                    ss += __shfl_xor(ss, 2);
                    ss += __shfl_xor(ss, 4);
                    ss += __shfl_xor(ss, 8);
                    float rms = rsqrtf(ss * (1.0f / 64.0f) + 1e-6f);
                    float xn[4];
#pragma unroll
                    for (int ni = 0; ni < 4; ++ni) xn[ni] = v[ni] * rms * wv[ni];
#pragma unroll
                    for (int ni = 0; ni < 4; ++ni) {
                        int d = 16 * ni + l15;
                        float c  = cos_t[s * 64 + d];
                        float sn = sin_t[s * 64 + d];
                        float rot = (ni < 2) ? -xn[ni + 2] : xn[ni - 2];
                        C[(size_t)row * N + colbase + d] = (short)f2b(xn[ni] * c + rot * sn);
                    }
                }
            }
            return;
        }
    }
#pragma unroll
    for (int ni = 0; ni < 4; ++ni) {
        float bvv = bias[colbase + 16 * ni + l15];
#pragma unroll
        for (int mi = 0; mi < 8; ++mi) {
#pragma unroll
            for (int r = 0; r < 4; ++r) {
                size_t row = (size_t)(m0 + wm * 128 + mi * 16 + lg * 4 + r);
                int    col = colbase + 16 * ni + l15;
                float v = acc[mi][ni][r] + bvv;
                if constexpr (sizeof(CT) == 4) C[row * N + col] = v;
                else                           C[row * N + col] = (short)f2b(v);
            }
        }
    }
}

// ---------------------------------------------------------------------------
// MFMA flash attention, 32x32x16 dataflow:
//  - ZERO-SHUFFLE PV (kept from r10, value-identical): V staged into Vt with
//    key bits 2<->3 swapped within each 16-key chunk (involution pi); the
//    lane's own P2[4c..4c+3] words then ARE the PV B-fragment verbatim.
//  - f32 SOFTMAX DENOMINATOR (reverted from r10's ones-MFMA, which pushed
//    absmax to 6.8e-3): ls accumulated in f32 with 4 independent
//    accumulators (breaks the serial add chain), folded + shfl_xor(32).
//  - v_max3 row max with 2 independent chains.
//  - defer-max (THR=11), exp2 domain, setprio around MFMA clusters.
// Grid 2048 (XCD-band remap), 256 thr = 4 waves; wave w: q rows [q0+32w,+32).
// ---------------------------------------------------------------------------
__global__ __launch_bounds__(256) void attn_mfma(const short* __restrict__ qkv,
                                                 short* __restrict__ attn) {
    __shared__ ushort_t pool[9216];            // 18 KiB: Ks[64][72] | Vt[64][72]
    ushort_t* Ks = pool;                       // [key][d], pitch 72
    ushort_t* Vt = pool + 4608;                // [d][key-slot], pitch 72

    const float SC  = 0.18033688011112042f;    // 0.125 * log2(e)
    const float THR = 11.0f;

    const int tid  = threadIdx.x;
    const int w    = tid >> 6;
    const int lane = tid & 63;
    const int l31  = lane & 31, l5 = lane >> 5;

    const int bid = blockIdx.x;
    const int xcd = bid & 7;
    const int jj_ = bid >> 3;
    const int bh  = xcd * 32 + (jj_ & 31);
    const int b   = bh >> 4, h = bh & 15;
    const int q0  = (jj_ >> 5) * 128;

    const short* qbase = qkv + (size_t)b * S_ * TDIM + h * HD_;
    const short* kb_ = qbase + DIM_;
    const short* vb_ = qbase + 2 * DIM_;

    s8v qf[4];
#pragma unroll
    for (int kc = 0; kc < 4; ++kc)
        qf[kc] = *(const s8v*)(qbase + (size_t)(q0 + w * 32 + l31) * TDIM + kc * 16 + l5 * 8);

    f32x16 of0 = {}, of1 = {};
    float m_s = -1e30f, l_s = 0.f;

    const int kr   = tid >> 3;
    const int kp8  = (tid & 7) * 8;
    const int vkp  = tid >> 3;         // key pair base k2 = 2*vkp
    const int va   = tid & 7;
    const int vp8  = va * 8;
    // slot for key-pair: swap bits 2<->3 within each 16, then XOR bank swizzle
    const int k2    = 2 * vkp;
    const int kperm = (k2 & 0x33) | ((k2 & 4) << 1) | ((k2 & 8) >> 1);
    const int vcol  = kperm ^ ((va & 3) << 4);
    const int vsw   = ((l31 >> 3) & 3) << 4;   // read-side XOR (slot space)

    s8v kA, kB, vA, vB;
    auto prefetch = [&](int kt) {
        const short* kbt = kb_ + (size_t)kt * 64 * TDIM;
        const short* vbt = vb_ + (size_t)kt * 64 * TDIM;
        kA = *(const s8v*)(kbt + (size_t)kr * TDIM + kp8);
        kB = *(const s8v*)(kbt + (size_t)(kr + 32) * TDIM + kp8);
        vA = *(const s8v*)(vbt + (size_t)k2 * TDIM + vp8);
        vB = *(const s8v*)(vbt + (size_t)(k2 + 1) * TDIM + vp8);
    };
    prefetch(0);

    for (int kt = 0; kt < 16; ++kt) {
        *(s8v*)&Ks[kr * 72 + kp8]        = kA;
        *(s8v*)&Ks[(kr + 32) * 72 + kp8] = kB;
#pragma unroll
        for (int j = 0; j < 8; ++j) {
            uint_t pk = (ushort_t)vA[j] | ((uint_t)(ushort_t)vB[j] << 16);
            *(uint_t*)&Vt[(vp8 + j) * 72 + vcol] = pk;
        }
        __syncthreads();

        if (kt < 15) prefetch(kt + 1);

        // ---- QK^T (swapped): st{0,1} = S^T[key-block][q] 32x32 frags
        f32x16 st0 = {}, st1 = {};
        __builtin_amdgcn_s_setprio(1);
#pragma unroll
        for (int kc = 0; kc < 4; ++kc) {
            s8v kf0 = *(const s8v*)&Ks[l31 * 72 + kc * 16 + l5 * 8];
            s8v kf1 = *(const s8v*)&Ks[(32 + l31) * 72 + kc * 16 + l5 * 8];
            st0 = mfma32_bf16(kf0, qf[kc], st0);
            st1 = mfma32_bf16(kf1, qf[kc], st1);
        }
        __builtin_amdgcn_s_setprio(0);

        // ---- row max: two independent v_max3 chains + one cross-half shfl
        float ma = fmaxf(st0[0], st1[0]);
        float mb = fmaxf(st0[8], st1[8]);
#pragma unroll
        for (int r = 1; r < 8; ++r) {
            ma = max3f(st0[r],     st1[r],     ma);
            mb = max3f(st0[8 + r], st1[8 + r], mb);
        }
        float mx = fmaxf(ma, mb);
        mx = fmaxf(mx, __shfl_xor(mx, 32));
        float mxs = mx * SC;

        if (!__all(mxs <= m_s + THR)) {          // wave-uniform, rare
            float mnew  = fmaxf(m_s, mxs);
            float alpha = exp2f(m_s - mnew);
            m_s = mnew;
            l_s *= alpha;
#pragma unroll
            for (int r = 0; r < 16; ++r) { of0[r] *= alpha; of1[r] *= alpha; }
        }

        // ---- P = exp2(st*SC - m); f32 denominator, 4 independent accumulators
        float la = 0.f, lb = 0.f, lc = 0.f, ld = 0.f;
#pragma unroll
        for (int r = 0; r < 16; r += 2) {
            float p00 = exp2f(__builtin_fmaf(st0[r],     SC, -m_s));
            float p01 = exp2f(__builtin_fmaf(st0[r + 1], SC, -m_s));
            float p10 = exp2f(__builtin_fmaf(st1[r],     SC, -m_s));
            float p11 = exp2f(__builtin_fmaf(st1[r + 1], SC, -m_s));
            st0[r] = p00; st0[r + 1] = p01;
            st1[r] = p10; st1[r + 1] = p11;
            la += p00; lb += p01; lc += p10; ld += p11;
        }
        float ls = (la + lb) + (lc + ld);
        ls += __shfl_xor(ls, 32);
        l_s += ls;

        // ---- P -> bf16 pairs; lane keys {8(i>>1)+4*l5+2(i&1), +1} per block
        uint_t P20[8], P21[8];
#pragma unroll
        for (int i = 0; i < 8; ++i) {
            P20[i] = cvt_pk_bf16(st0[2 * i], st0[2 * i + 1]);
            P21[i] = cvt_pk_bf16(st1[2 * i], st1[2 * i + 1]);
        }

        // ---- PV: zero-shuffle B-frags (pi-permuted Vt slots)
        __builtin_amdgcn_s_setprio(1);
#pragma unroll
        for (int kb = 0; kb < 2; ++kb) {
            const uint_t* P2 = kb ? P21 : P20;
#pragma unroll
            for (int c = 0; c < 2; ++c) {
                union { uint_t u[4]; s8v v; } pf;
                pf.u[0] = P2[4 * c + 0];
                pf.u[1] = P2[4 * c + 1];
                pf.u[2] = P2[4 * c + 2];
                pf.u[3] = P2[4 * c + 3];

                int kcol = (kb * 32 + c * 16 + l5 * 8) ^ vsw;
                s8v vf0 = *(const s8v*)&Vt[l31 * 72 + kcol];
                s8v vf1 = *(const s8v*)&Vt[(32 + l31) * 72 + kcol];
                of0 = mfma32_bf16(vf0, pf.v, of0);
                of1 = mfma32_bf16(vf1, pf.v, of1);
            }
        }
        __builtin_amdgcn_s_setprio(0);
        __syncthreads();
    }

    // ---- epilogue: O^T -> LDS transpose -> coalesced 16B stores
    float inv = 1.0f / l_s;
    ushort_t* OL = pool + w * 2304;        // per-wave [32 q][72], wave-private
#pragma unroll
    for (int r = 0; r < 16; ++r) {
        int d = (r & 3) + 8 * (r >> 2) + 4 * l5;
        OL[l31 * 72 + d]      = f2b(of0[r] * inv);
        OL[l31 * 72 + 32 + d] = f2b(of1[r] * inv);
    }
#pragma unroll
    for (int i = 0; i < 4; ++i) {
        int idx = lane + i * 64;
        int row = idx >> 3, ch = idx & 7;
        *(s8v*)&attn[((size_t)b * S_ + q0 + w * 32 + row) * DIM_ + h * HD_ + ch * 8] =
            *(const s8v*)&OL[row * 72 + ch * 8];
    }
}

// ---------------------------------------------------------------------------
extern "C" void kernel_launch(void* const* d_in, const int* in_sizes, int n_in,
                              void* d_out, int out_size, void* d_ws, size_t ws_size,
                              hipStream_t stream) {
    const float* x        = (const float*)d_in[0];
    const float* w_qkv    = (const float*)d_in[1];
    const float* b_qkv    = (const float*)d_in[2];
    const float* q_norm_w = (const float*)d_in[3];
    const float* k_norm_w = (const float*)d_in[4];
    const float* w_out    = (const float*)d_in[5];
    const float* b_out    = (const float*)d_in[6];
    float* out = (float*)d_out;

    const size_t OFF_QKV = 0;                          //  96 MiB: qkv bf16
    const size_t OFF_ATT = 100663296;                  //  32 MiB: attn bf16
    const size_t OFF_XB  = OFF_ATT + 33554432;         //  32 MiB: x bf16
    const size_t OFF_WQ  = OFF_XB + 33554432;          //   6 MiB: w_qkv^T bf16
    const size_t OFF_WO  = OFF_WQ + 6291456;           //   2 MiB: w_out^T bf16
    const size_t OFF_CT  = OFF_WO + 2097152;           // 256 KiB: cos table
    const size_t OFF_ST  = OFF_CT + 262144;            // 256 KiB: sin table
    const size_t NEED    = OFF_ST + 262144;

    if (ws_size < NEED) {
        hipMemsetAsync(d_out, 0, (size_t)out_size * sizeof(float), stream);
        return;
    }

    char* ws = (char*)d_ws;
    short* qkv   = (short*)(ws + OFF_QKV);
    short* attnb = (short*)(ws + OFF_ATT);
    short* xb    = (short*)(ws + OFF_XB);
    short* wqkvT = (short*)(ws + OFF_WQ);
    short* woutT = (short*)(ws + OFF_WO);
    float* cos_t = (float*)(ws + OFF_CT);
    float* sin_t = (float*)(ws + OFF_ST);

    // 0: tables, conversions, weight transposes
    rope_tables<<<dim3(256), dim3(256), 0, stream>>>(cos_t, sin_t);
    f32_to_bf16_vec<<<dim3(8192), dim3(256), 0, stream>>>(x, xb, 2097152);
    transpose_to_bf16<<<dim3(96, 32), dim3(256), 0, stream>>>(w_qkv, wqkvT, 1024, 3072);
    transpose_to_bf16<<<dim3(32, 32), dim3(256), 0, stream>>>(w_out, woutT, 1024, 1024);

    // 1: qkv = x @ w_qkv + b_qkv, fused RMSNorm+RoPE epilogue on q,k columns.
    gemm8ph<short, true><<<dim3(768), dim3(512), 0, stream>>>(
        xb, wqkvT, b_qkv, qkv, 16384, 3072, 1024, 12,
        q_norm_w, k_norm_w, cos_t, sin_t);

    // 2: flash attention -> attnb (bf16)
    attn_mfma<<<dim3(2048), dim3(256), 0, stream>>>(qkv, attnb);

    // 3: out = attn @ w_out + b_out (fp32 out)
    gemm8ph<float, false><<<dim3(256), dim3(512), 0, stream>>>(
        attnb, woutT, b_out, out, 16384, 1024, 1024, 4,
        nullptr, nullptr, nullptr, nullptr);
}

// Round 12
// 307.882 us; speedup vs baseline: 1.1557x; 1.0345x over previous
//
#include <hip/hip_runtime.h>
#include <cstdint>
#include <cstddef>

#define B_    16
#define S_    1024
#define DIM_  1024
#define H_    16
#define HD_   64
#define TDIM  3072   // 3*DIM

typedef unsigned short ushort_t;
typedef unsigned int   uint_t;
typedef __attribute__((ext_vector_type(8)))  short s8v;    // 8 bf16 = 4 VGPRs
typedef __attribute__((ext_vector_type(4)))  float f32x4;
typedef __attribute__((ext_vector_type(16))) float f32x16;

__device__ __forceinline__ float b2f(ushort_t u) {
    union { uint_t i; float f; } t; t.i = (uint_t)u << 16; return t.f;
}
__device__ __forceinline__ ushort_t f2b(float f) {
    union { float f; uint_t i; } t; t.f = f;
    uint_t r = t.i + 0x7FFFu + ((t.i >> 16) & 1u);   // RNE
    return (ushort_t)(r >> 16);
}
__device__ __forceinline__ uint_t cvt_pk_bf16(float a, float b) {
    uint_t r;
    asm("v_cvt_pk_bf16_f32 %0, %1, %2" : "=v"(r) : "v"(a), "v"(b));
    return r;
}
__device__ __forceinline__ float max3f(float a, float b, float c) {
    float r;
    asm("v_max3_f32 %0, %1, %2, %3" : "=v"(r) : "v"(a), "v"(b), "v"(c));
    return r;
}

// 16x16x32: D[m][n] += sum_k A[m,k]*B[k,n]
// D-frag (HW-verified m89/m91): col=lane&15, row=(lane>>4)*4+reg.
__device__ __forceinline__ f32x4 mfma_bf16(s8v a, s8v b, f32x4 c) {
    asm volatile("v_mfma_f32_16x16x32_bf16 %0, %1, %2, %0" : "+v"(c) : "v"(a), "v"(b));
    return c;
}
// 32x32x16: D-frag (HW-verified m74/m101): col=lane&31, row=(reg&3)+8*(reg>>2)+4*(lane>>5)
__device__ __forceinline__ f32x16 mfma32_bf16(s8v a, s8v b, f32x16 c) {
    asm volatile("v_mfma_f32_32x32x16_bf16 %0, %1, %2, %0" : "+v"(c) : "v"(a), "v"(b));
    return c;
}

// async global->LDS, 16B per lane; LDS dest = wave-uniform base + lane*16.
__device__ __forceinline__ void gload16(const void* g, void* l) {
    __builtin_amdgcn_global_load_lds(
        (const __attribute__((address_space(1))) uint_t*)g,
        (__attribute__((address_space(3))) uint_t*)l, 16, 0, 0);
}

// raw barrier (no compiler vmcnt drain) + explicit vm waits
__device__ __forceinline__ void bar() {
    asm volatile("" ::: "memory");
    __builtin_amdgcn_s_barrier();
    asm volatile("" ::: "memory");
}
__device__ __forceinline__ void wait_vm0() {
    asm volatile("s_waitcnt vmcnt(0)" ::: "memory");
}
__device__ __forceinline__ void wait_vm4() {
    asm volatile("s_waitcnt vmcnt(4)" ::: "memory");
}

// ---------------------------------------------------------------------------
// fp32 -> bf16, 8 elements/thread
// ---------------------------------------------------------------------------
__global__ __launch_bounds__(256) void f32_to_bf16_vec(const float* __restrict__ src,
                                                       short* __restrict__ dst, int n8) {
    int i = blockIdx.x * 256 + threadIdx.x;
    if (i < n8) {
        float4 a = *(const float4*)(src + (size_t)i * 8);
        float4 b = *(const float4*)(src + (size_t)i * 8 + 4);
        s8v t;
        t[0] = (short)f2b(a.x); t[1] = (short)f2b(a.y);
        t[2] = (short)f2b(a.z); t[3] = (short)f2b(a.w);
        t[4] = (short)f2b(b.x); t[5] = (short)f2b(b.y);
        t[6] = (short)f2b(b.z); t[7] = (short)f2b(b.w);
        *(s8v*)(dst + (size_t)i * 8) = t;
    }
}

// ---------------------------------------------------------------------------
// RoPE cos/sin tables [S][HD] fp32
// ---------------------------------------------------------------------------
__global__ __launch_bounds__(256) void rope_tables(float* __restrict__ cos_t,
                                                   float* __restrict__ sin_t) {
    int idx = blockIdx.x * 256 + threadIdx.x;     // 0 .. 65535
    int s = idx >> 6;
    int d = idx & 63;
    int pos = (d < 32) ? (s >> 5) : (s & 31);
    int i   = (d & 31) >> 1;
    float freq  = expf(-(float)i * 0.5756462732485115f);   // ln(10000)/16
    float angle = (float)pos * 0.5f * freq;
    cos_t[idx] = cosf(angle);
    sin_t[idx] = sinf(angle);
}

// ---------------------------------------------------------------------------
// W[K][N] fp32 -> WT[N][K] bf16  (32x32 LDS tile transpose)
// ---------------------------------------------------------------------------
__global__ __launch_bounds__(256) void transpose_to_bf16(const float* __restrict__ Wsrc,
                                                         short* __restrict__ WT,
                                                         int K, int N) {
    __shared__ float t[32][33];
    int tx = threadIdx.x & 31, ty = threadIdx.x >> 5;   // ty 0..7
    int n0 = blockIdx.x * 32, k0 = blockIdx.y * 32;
#pragma unroll
    for (int i = 0; i < 4; ++i)
        t[ty + 8 * i][tx] = Wsrc[(size_t)(k0 + ty + 8 * i) * N + n0 + tx];
    __syncthreads();
#pragma unroll
    for (int i = 0; i < 4; ++i)
        WT[(size_t)(n0 + ty + 8 * i) * K + k0 + tx] = (short)f2b(t[tx][ty + 8 * i]);
}

// ---------------------------------------------------------------------------
// 8-phase 256x256 bf16 MFMA GEMM with COUNTED vmcnt (T4):
//   A double-buffered (2x32K), B triple-buffered (3x32K) -> 160 KiB LDS.
//   Tile t: ph1 stages A(t+1), ph2 stages B(t+2).
//   Boundary wait = vmcnt(4): only B(t+2)'s 4 loads stay in flight;
//   A(t+1), B(t+1) (the oldest 8) are complete (m135 oldest-first semantics).
//   Buffer reuse is fenced by the t-1 boundary barrier.
//   XOR-swizzled LDS (both-sides involution), zero bank conflicts (r11 PMC).
//   NORM: fused per-head RMSNorm + RoPE epilogue for columns < 2048 (q,k).
// ---------------------------------------------------------------------------
template<typename CT, bool NORM>
__global__ __launch_bounds__(512, 2) void gemm8ph(
        const short* __restrict__ A, const short* __restrict__ BT,
        const float* __restrict__ bias, CT* __restrict__ C,
        int M, int N, int K, int NX,
        const float* __restrict__ qw, const float* __restrict__ kw,
        const float* __restrict__ cos_t, const float* __restrict__ sin_t) {
    __shared__ short As[2][256 * 64];   // 64 KiB
    __shared__ short Bs[3][256 * 64];   // 96 KiB

    const int tid  = threadIdx.x;
    const int w    = tid >> 6;           // 0..7
    const int lane = tid & 63;
    const int l15  = lane & 15, lg = lane >> 4;
    const int wm = w >> 2, wn = w & 3;   // wave grid 2(M) x 4(N)

    const int nwg  = gridDim.x;
    const int cpx  = nwg >> 3;
    const int wgid = (blockIdx.x & 7) * cpx + (blockIdx.x >> 3);
    const int bx = wgid % NX, by = wgid / NX;
    const int m0 = by * 256, n0 = bx * 256;

    const int NT = K >> 6;               // K-tiles of 64

    const int sgrow = w * 8 + (lane >> 3);            // + j*64
    const int ksrc  = (((lane & 7) ^ (lane >> 3)) * 8);

    auto stageA = [&](int t, int buf) {
        const size_t k0 = (size_t)t * 64;
#pragma unroll
        for (int j = 0; j < 4; ++j)
            gload16(A + (size_t)(m0 + j * 64 + sgrow) * K + k0 + ksrc,
                    &As[buf][(j * 64 + w * 8) * 64]);
    };
    auto stageB = [&](int t, int buf) {
        const size_t k0 = (size_t)t * 64;
#pragma unroll
        for (int j = 0; j < 4; ++j)
            gload16(BT + (size_t)(n0 + j * 64 + sgrow) * K + k0 + ksrc,
                    &Bs[buf][(j * 64 + w * 8) * 64]);
    };

    // prologue: A0, B0, B1 in flight; wait for A0,B0 (B1 stays flying)
    stageA(0, 0);
    stageB(0, 0);
    stageB(1, 1);
    wait_vm4();
    bar();

    f32x4 acc[8][4] = {};
    s8v a_f[4][2];
    s8v b_f[4][2];

    const int swz = l15 & 7;

    int bufB = 0;
    for (int t = 0; t < NT; ++t) {
        const int bufA = t & 1;
        const int nbufB = (bufB == 2) ? 0 : bufB + 1;   // (t+1)%3
        const int sbufB = (nbufB == 2) ? 0 : nbufB + 1; // (t+2)%3

        // ---- phase 1: read A-mh0 + B-nh0/1; stage A(t+1); MFMA (mh0, ni0-1)
#pragma unroll
        for (int i = 0; i < 4; ++i) {
            int row = wm * 128 + i * 16 + l15;
#pragma unroll
            for (int kk = 0; kk < 2; ++kk)
                a_f[i][kk] = *(const s8v*)&As[bufA][row * 64 + (((kk * 4 + lg) ^ swz) * 8)];
        }
#pragma unroll
        for (int ni = 0; ni < 2; ++ni) {
            int row = wn * 64 + ni * 16 + l15;
#pragma unroll
            for (int kk = 0; kk < 2; ++kk)
                b_f[ni][kk] = *(const s8v*)&Bs[bufB][row * 64 + (((kk * 4 + lg) ^ swz) * 8)];
        }
        if (t + 1 < NT) stageA(t + 1, bufA ^ 1);
        bar();
        __builtin_amdgcn_s_setprio(1);
#pragma unroll
        for (int i = 0; i < 4; ++i)
#pragma unroll
            for (int ni = 0; ni < 2; ++ni)
#pragma unroll
                for (int kk = 0; kk < 2; ++kk)
                    acc[i][ni] = mfma_bf16(a_f[i][kk], b_f[ni][kk], acc[i][ni]);
        __builtin_amdgcn_s_setprio(0);
        bar();

        // ---- phase 2: read B-nh2/3; stage B(t+2); MFMA (mh0, ni2-3)
#pragma unroll
        for (int ni = 2; ni < 4; ++ni) {
            int row = wn * 64 + ni * 16 + l15;
#pragma unroll
            for (int kk = 0; kk < 2; ++kk)
                b_f[ni][kk] = *(const s8v*)&Bs[bufB][row * 64 + (((kk * 4 + lg) ^ swz) * 8)];
        }
        if (t + 2 < NT) stageB(t + 2, sbufB);
        bar();
        __builtin_amdgcn_s_setprio(1);
#pragma unroll
        for (int i = 0; i < 4; ++i)
#pragma unroll
            for (int ni = 2; ni < 4; ++ni)
#pragma unroll
                for (int kk = 0; kk < 2; ++kk)
                    acc[i][ni] = mfma_bf16(a_f[i][kk], b_f[ni][kk], acc[i][ni]);
        __builtin_amdgcn_s_setprio(0);
        bar();

        // ---- phase 3: read A-mh1; MFMA (mh1, ni0-1)
#pragma unroll
        for (int i = 0; i < 4; ++i) {
            int row = wm * 128 + 64 + i * 16 + l15;
#pragma unroll
            for (int kk = 0; kk < 2; ++kk)
                a_f[i][kk] = *(const s8v*)&As[bufA][row * 64 + (((kk * 4 + lg) ^ swz) * 8)];
        }
        bar();
        __builtin_amdgcn_s_setprio(1);
#pragma unroll
        for (int i = 0; i < 4; ++i)
#pragma unroll
            for (int ni = 0; ni < 2; ++ni)
#pragma unroll
                for (int kk = 0; kk < 2; ++kk)
                    acc[4 + i][ni] = mfma_bf16(a_f[i][kk], b_f[ni][kk], acc[4 + i][ni]);
        __builtin_amdgcn_s_setprio(0);
        bar();

        // ---- phase 4: MFMA (mh1, ni2-3); COUNTED boundary wait
        __builtin_amdgcn_s_setprio(1);
#pragma unroll
        for (int i = 0; i < 4; ++i)
#pragma unroll
            for (int ni = 2; ni < 4; ++ni)
#pragma unroll
                for (int kk = 0; kk < 2; ++kk)
                    acc[4 + i][ni] = mfma_bf16(a_f[i][kk], b_f[ni][kk], acc[4 + i][ni]);
        __builtin_amdgcn_s_setprio(0);
        if (t < NT - 2) wait_vm4();   // A(t+1),B(t+1) done; B(t+2) stays in flight
        else            wait_vm0();   // tail: drain
        bar();
        bufB = nbufB;
    }

    // ---------------- epilogue ----------------
    const int colbase = n0 + wn * 64;
    if constexpr (NORM) {
        if (colbase < 2048) {
            const float* nw = (colbase < 1024) ? qw : kw;
            float wv[4], bv[4];
#pragma unroll
            for (int ni = 0; ni < 4; ++ni) {
                wv[ni] = nw[16 * ni + l15];
                bv[ni] = bias[colbase + 16 * ni + l15];
            }
#pragma unroll
            for (int mi = 0; mi < 8; ++mi) {
#pragma unroll
                for (int r = 0; r < 4; ++r) {
                    int row = m0 + wm * 128 + mi * 16 + lg * 4 + r;
                    int s = row & (S_ - 1);
                    float v[4];
#pragma unroll
                    for (int ni = 0; ni < 4; ++ni) v[ni] = acc[mi][ni][r] + bv[ni];
                    float ss = v[0]*v[0] + v[1]*v[1] + v[2]*v[2] + v[3]*v[3];
                    ss += __shfl_xor(ss, 1);
                    ss += __shfl_xor(ss, 2);
                    ss += __shfl_xor(ss, 4);
                    ss += __shfl_xor(ss, 8);
                    float rms = rsqrtf(ss * (1.0f / 64.0f) + 1e-6f);
                    float xn[4];
#pragma unroll
                    for (int ni = 0; ni < 4; ++ni) xn[ni] = v[ni] * rms * wv[ni];
#pragma unroll
                    for (int ni = 0; ni < 4; ++ni) {
                        int d = 16 * ni + l15;
                        float c  = cos_t[s * 64 + d];
                        float sn = sin_t[s * 64 + d];
                        float rot = (ni < 2) ? -xn[ni + 2] : xn[ni - 2];
                        C[(size_t)row * N + colbase + d] = (short)f2b(xn[ni] * c + rot * sn);
                    }
                }
            }
            return;
        }
    }
#pragma unroll
    for (int ni = 0; ni < 4; ++ni) {
        float bvv = bias[colbase + 16 * ni + l15];
#pragma unroll
        for (int mi = 0; mi < 8; ++mi) {
#pragma unroll
            for (int r = 0; r < 4; ++r) {
                size_t row = (size_t)(m0 + wm * 128 + mi * 16 + lg * 4 + r);
                int    col = colbase + 16 * ni + l15;
                float v = acc[mi][ni][r] + bvv;
                if constexpr (sizeof(CT) == 4) C[row * N + col] = v;
                else                           C[row * N + col] = (short)f2b(v);
            }
        }
    }
}

// ---------------------------------------------------------------------------
// MFMA flash attention, 32x32x16 dataflow (round-11 version, unchanged):
// zero-shuffle PV (pi-permuted Vt), f32 denominator (4 acc), max3, defer-max.
// ---------------------------------------------------------------------------
__global__ __launch_bounds__(256) void attn_mfma(const short* __restrict__ qkv,
                                                 short* __restrict__ attn) {
    __shared__ ushort_t pool[9216];            // 18 KiB: Ks[64][72] | Vt[64][72]
    ushort_t* Ks = pool;                       // [key][d], pitch 72
    ushort_t* Vt = pool + 4608;                // [d][key-slot], pitch 72

    const float SC  = 0.18033688011112042f;    // 0.125 * log2(e)
    const float THR = 11.0f;

    const int tid  = threadIdx.x;
    const int w    = tid >> 6;
    const int lane = tid & 63;
    const int l31  = lane & 31, l5 = lane >> 5;

    const int bid = blockIdx.x;
    const int xcd = bid & 7;
    const int jj_ = bid >> 3;
    const int bh  = xcd * 32 + (jj_ & 31);
    const int b   = bh >> 4, h = bh & 15;
    const int q0  = (jj_ >> 5) * 128;

    const short* qbase = qkv + (size_t)b * S_ * TDIM + h * HD_;
    const short* kb_ = qbase + DIM_;
    const short* vb_ = qbase + 2 * DIM_;

    s8v qf[4];
#pragma unroll
    for (int kc = 0; kc < 4; ++kc)
        qf[kc] = *(const s8v*)(qbase + (size_t)(q0 + w * 32 + l31) * TDIM + kc * 16 + l5 * 8);

    f32x16 of0 = {}, of1 = {};
    float m_s = -1e30f, l_s = 0.f;

    const int kr   = tid >> 3;
    const int kp8  = (tid & 7) * 8;
    const int vkp  = tid >> 3;         // key pair base k2 = 2*vkp
    const int va   = tid & 7;
    const int vp8  = va * 8;
    const int k2    = 2 * vkp;
    const int kperm = (k2 & 0x33) | ((k2 & 4) << 1) | ((k2 & 8) >> 1);
    const int vcol  = kperm ^ ((va & 3) << 4);
    const int vsw   = ((l31 >> 3) & 3) << 4;   // read-side XOR (slot space)

    s8v kA, kB, vA, vB;
    auto prefetch = [&](int kt) {
        const short* kbt = kb_ + (size_t)kt * 64 * TDIM;
        const short* vbt = vb_ + (size_t)kt * 64 * TDIM;
        kA = *(const s8v*)(kbt + (size_t)kr * TDIM + kp8);
        kB = *(const s8v*)(kbt + (size_t)(kr + 32) * TDIM + kp8);
        vA = *(const s8v*)(vbt + (size_t)k2 * TDIM + vp8);
        vB = *(const s8v*)(vbt + (size_t)(k2 + 1) * TDIM + vp8);
    };
    prefetch(0);

    for (int kt = 0; kt < 16; ++kt) {
        *(s8v*)&Ks[kr * 72 + kp8]        = kA;
        *(s8v*)&Ks[(kr + 32) * 72 + kp8] = kB;
#pragma unroll
        for (int j = 0; j < 8; ++j) {
            uint_t pk = (ushort_t)vA[j] | ((uint_t)(ushort_t)vB[j] << 16);
            *(uint_t*)&Vt[(vp8 + j) * 72 + vcol] = pk;
        }
        __syncthreads();

        if (kt < 15) prefetch(kt + 1);

        // ---- QK^T (swapped): st{0,1} = S^T[key-block][q] 32x32 frags
        f32x16 st0 = {}, st1 = {};
        __builtin_amdgcn_s_setprio(1);
#pragma unroll
        for (int kc = 0; kc < 4; ++kc) {
            s8v kf0 = *(const s8v*)&Ks[l31 * 72 + kc * 16 + l5 * 8];
            s8v kf1 = *(const s8v*)&Ks[(32 + l31) * 72 + kc * 16 + l5 * 8];
            st0 = mfma32_bf16(kf0, qf[kc], st0);
            st1 = mfma32_bf16(kf1, qf[kc], st1);
        }
        __builtin_amdgcn_s_setprio(0);

        // ---- row max: two independent v_max3 chains + one cross-half shfl
        float ma = fmaxf(st0[0], st1[0]);
        float mb = fmaxf(st0[8], st1[8]);
#pragma unroll
        for (int r = 1; r < 8; ++r) {
            ma = max3f(st0[r],     st1[r],     ma);
            mb = max3f(st0[8 + r], st1[8 + r], mb);
        }
        float mx = fmaxf(ma, mb);
        mx = fmaxf(mx, __shfl_xor(mx, 32));
        float mxs = mx * SC;

        if (!__all(mxs <= m_s + THR)) {          // wave-uniform, rare
            float mnew  = fmaxf(m_s, mxs);
            float alpha = exp2f(m_s - mnew);
            m_s = mnew;
            l_s *= alpha;
#pragma unroll
            for (int r = 0; r < 16; ++r) { of0[r] *= alpha; of1[r] *= alpha; }
        }

        // ---- P = exp2(st*SC - m); f32 denominator, 4 independent accumulators
        float la = 0.f, lb = 0.f, lc = 0.f, ld = 0.f;
#pragma unroll
        for (int r = 0; r < 16; r += 2) {
            float p00 = exp2f(__builtin_fmaf(st0[r],     SC, -m_s));
            float p01 = exp2f(__builtin_fmaf(st0[r + 1], SC, -m_s));
            float p10 = exp2f(__builtin_fmaf(st1[r],     SC, -m_s));
            float p11 = exp2f(__builtin_fmaf(st1[r + 1], SC, -m_s));
            st0[r] = p00; st0[r + 1] = p01;
            st1[r] = p10; st1[r + 1] = p11;
            la += p00; lb += p01; lc += p10; ld += p11;
        }
        float ls = (la + lb) + (lc + ld);
        ls += __shfl_xor(ls, 32);
        l_s += ls;

        // ---- P -> bf16 pairs
        uint_t P20[8], P21[8];
#pragma unroll
        for (int i = 0; i < 8; ++i) {
            P20[i] = cvt_pk_bf16(st0[2 * i], st0[2 * i + 1]);
            P21[i] = cvt_pk_bf16(st1[2 * i], st1[2 * i + 1]);
        }

        // ---- PV: zero-shuffle B-frags (pi-permuted Vt slots)
        __builtin_amdgcn_s_setprio(1);
#pragma unroll
        for (int kb = 0; kb < 2; ++kb) {
            const uint_t* P2 = kb ? P21 : P20;
#pragma unroll
            for (int c = 0; c < 2; ++c) {
                union { uint_t u[4]; s8v v; } pf;
                pf.u[0] = P2[4 * c + 0];
                pf.u[1] = P2[4 * c + 1];
                pf.u[2] = P2[4 * c + 2];
                pf.u[3] = P2[4 * c + 3];

                int kcol = (kb * 32 + c * 16 + l5 * 8) ^ vsw;
                s8v vf0 = *(const s8v*)&Vt[l31 * 72 + kcol];
                s8v vf1 = *(const s8v*)&Vt[(32 + l31) * 72 + kcol];
                of0 = mfma32_bf16(vf0, pf.v, of0);
                of1 = mfma32_bf16(vf1, pf.v, of1);
            }
        }
        __builtin_amdgcn_s_setprio(0);
        __syncthreads();
    }

    // ---- epilogue: O^T -> LDS transpose -> coalesced 16B stores
    float inv = 1.0f / l_s;
    ushort_t* OL = pool + w * 2304;        // per-wave [32 q][72], wave-private
#pragma unroll
    for (int r = 0; r < 16; ++r) {
        int d = (r & 3) + 8 * (r >> 2) + 4 * l5;
        OL[l31 * 72 + d]      = f2b(of0[r] * inv);
        OL[l31 * 72 + 32 + d] = f2b(of1[r] * inv);
    }
#pragma unroll
    for (int i = 0; i < 4; ++i) {
        int idx = lane + i * 64;
        int row = idx >> 3, ch = idx & 7;
        *(s8v*)&attn[((size_t)b * S_ + q0 + w * 32 + row) * DIM_ + h * HD_ + ch * 8] =
            *(const s8v*)&OL[row * 72 + ch * 8];
    }
}

// ---------------------------------------------------------------------------
extern "C" void kernel_launch(void* const* d_in, const int* in_sizes, int n_in,
                              void* d_out, int out_size, void* d_ws, size_t ws_size,
                              hipStream_t stream) {
    const float* x        = (const float*)d_in[0];
    const float* w_qkv    = (const float*)d_in[1];
    const float* b_qkv    = (const float*)d_in[2];
    const float* q_norm_w = (const float*)d_in[3];
    const float* k_norm_w = (const float*)d_in[4];
    const float* w_out    = (const float*)d_in[5];
    const float* b_out    = (const float*)d_in[6];
    float* out = (float*)d_out;

    const size_t OFF_QKV = 0;                          //  96 MiB: qkv bf16
    const size_t OFF_ATT = 100663296;                  //  32 MiB: attn bf16
    const size_t OFF_XB  = OFF_ATT + 33554432;         //  32 MiB: x bf16
    const size_t OFF_WQ  = OFF_XB + 33554432;          //   6 MiB: w_qkv^T bf16
    const size_t OFF_WO  = OFF_WQ + 6291456;           //   2 MiB: w_out^T bf16
    const size_t OFF_CT  = OFF_WO + 2097152;           // 256 KiB: cos table
    const size_t OFF_ST  = OFF_CT + 262144;            // 256 KiB: sin table
    const size_t NEED    = OFF_ST + 262144;

    if (ws_size < NEED) {
        hipMemsetAsync(d_out, 0, (size_t)out_size * sizeof(float), stream);
        return;
    }

    char* ws = (char*)d_ws;
    short* qkv   = (short*)(ws + OFF_QKV);
    short* attnb = (short*)(ws + OFF_ATT);
    short* xb    = (short*)(ws + OFF_XB);
    short* wqkvT = (short*)(ws + OFF_WQ);
    short* woutT = (short*)(ws + OFF_WO);
    float* cos_t = (float*)(ws + OFF_CT);
    float* sin_t = (float*)(ws + OFF_ST);

    // 0: tables, conversions, weight transposes
    rope_tables<<<dim3(256), dim3(256), 0, stream>>>(cos_t, sin_t);
    f32_to_bf16_vec<<<dim3(8192), dim3(256), 0, stream>>>(x, xb, 2097152);
    transpose_to_bf16<<<dim3(96, 32), dim3(256), 0, stream>>>(w_qkv, wqkvT, 1024, 3072);
    transpose_to_bf16<<<dim3(32, 32), dim3(256), 0, stream>>>(w_out, woutT, 1024, 1024);

    // 1: qkv = x @ w_qkv + b_qkv, fused RMSNorm+RoPE epilogue on q,k columns.
    gemm8ph<short, true><<<dim3(768), dim3(512), 0, stream>>>(
        xb, wqkvT, b_qkv, qkv, 16384, 3072, 1024, 12,
        q_norm_w, k_norm_w, cos_t, sin_t);

    // 2: flash attention -> attnb (bf16)
    attn_mfma<<<dim3(2048), dim3(256), 0, stream>>>(qkv, attnb);

    // 3: out = attn @ w_out + b_out (fp32 out)
    gemm8ph<float, false><<<dim3(256), dim3(512), 0, stream>>>(
        attnb, woutT, b_out, out, 16384, 1024, 1024, 4,
        nullptr, nullptr, nullptr, nullptr);
}

// Round 13
// 296.456 us; speedup vs baseline: 1.2003x; 1.0385x over previous
//
#include <hip/hip_runtime.h>
#include <cstdint>
#include <cstddef>

#define B_    16
#define S_    1024
#define DIM_  1024
#define H_    16
#define HD_   64
#define TDIM  3072   // 3*DIM

typedef unsigned short ushort_t;
typedef unsigned int   uint_t;
typedef __attribute__((ext_vector_type(8)))  short s8v;    // 8 bf16 = 4 VGPRs
typedef __attribute__((ext_vector_type(4)))  float f32x4;
typedef __attribute__((ext_vector_type(16))) float f32x16;

__device__ __forceinline__ float b2f(ushort_t u) {
    union { uint_t i; float f; } t; t.i = (uint_t)u << 16; return t.f;
}
__device__ __forceinline__ ushort_t f2b(float f) {
    union { float f; uint_t i; } t; t.f = f;
    uint_t r = t.i + 0x7FFFu + ((t.i >> 16) & 1u);   // RNE
    return (ushort_t)(r >> 16);
}
__device__ __forceinline__ uint_t cvt_pk_bf16(float a, float b) {
    uint_t r;
    asm("v_cvt_pk_bf16_f32 %0, %1, %2" : "=v"(r) : "v"(a), "v"(b));
    return r;
}
__device__ __forceinline__ float max3f(float a, float b, float c) {
    float r;
    asm("v_max3_f32 %0, %1, %2, %3" : "=v"(r) : "v"(a), "v"(b), "v"(c));
    return r;
}

// 16x16x32: D[m][n] += sum_k A[m,k]*B[k,n]
// D-frag (HW-verified m89/m91): col=lane&15, row=(lane>>4)*4+reg.
__device__ __forceinline__ f32x4 mfma_bf16(s8v a, s8v b, f32x4 c) {
    asm volatile("v_mfma_f32_16x16x32_bf16 %0, %1, %2, %0" : "+v"(c) : "v"(a), "v"(b));
    return c;
}
// 32x32x16: D-frag (HW-verified m74/m101): col=lane&31, row=(reg&3)+8*(reg>>2)+4*(lane>>5)
__device__ __forceinline__ f32x16 mfma32_bf16(s8v a, s8v b, f32x16 c) {
    asm volatile("v_mfma_f32_32x32x16_bf16 %0, %1, %2, %0" : "+v"(c) : "v"(a), "v"(b));
    return c;
}

// async global->LDS, 16B per lane; LDS dest = wave-uniform base + lane*16.
__device__ __forceinline__ void gload16(const void* g, void* l) {
    __builtin_amdgcn_global_load_lds(
        (const __attribute__((address_space(1))) uint_t*)g,
        (__attribute__((address_space(3))) uint_t*)l, 16, 0, 0);
}

// raw barrier (no compiler vmcnt drain) + explicit vm waits
__device__ __forceinline__ void bar() {
    asm volatile("" ::: "memory");
    __builtin_amdgcn_s_barrier();
    asm volatile("" ::: "memory");
}
__device__ __forceinline__ void wait_vm0() {
    asm volatile("s_waitcnt vmcnt(0)" ::: "memory");
}
__device__ __forceinline__ void wait_vm4() {
    asm volatile("s_waitcnt vmcnt(4)" ::: "memory");
}

// ---------------------------------------------------------------------------
// fp32 -> bf16, 8 elements/thread
// ---------------------------------------------------------------------------
__global__ __launch_bounds__(256) void f32_to_bf16_vec(const float* __restrict__ src,
                                                       short* __restrict__ dst, int n8) {
    int i = blockIdx.x * 256 + threadIdx.x;
    if (i < n8) {
        float4 a = *(const float4*)(src + (size_t)i * 8);
        float4 b = *(const float4*)(src + (size_t)i * 8 + 4);
        s8v t;
        t[0] = (short)f2b(a.x); t[1] = (short)f2b(a.y);
        t[2] = (short)f2b(a.z); t[3] = (short)f2b(a.w);
        t[4] = (short)f2b(b.x); t[5] = (short)f2b(b.y);
        t[6] = (short)f2b(b.z); t[7] = (short)f2b(b.w);
        *(s8v*)(dst + (size_t)i * 8) = t;
    }
}

// ---------------------------------------------------------------------------
// RoPE cos/sin tables [S][HD] fp32
// ---------------------------------------------------------------------------
__global__ __launch_bounds__(256) void rope_tables(float* __restrict__ cos_t,
                                                   float* __restrict__ sin_t) {
    int idx = blockIdx.x * 256 + threadIdx.x;     // 0 .. 65535
    int s = idx >> 6;
    int d = idx & 63;
    int pos = (d < 32) ? (s >> 5) : (s & 31);
    int i   = (d & 31) >> 1;
    float freq  = expf(-(float)i * 0.5756462732485115f);   // ln(10000)/16
    float angle = (float)pos * 0.5f * freq;
    cos_t[idx] = cosf(angle);
    sin_t[idx] = sinf(angle);
}

// ---------------------------------------------------------------------------
// W[K][N] fp32 -> WT[N][K] bf16  (32x32 LDS tile transpose)
// ---------------------------------------------------------------------------
__global__ __launch_bounds__(256) void transpose_to_bf16(const float* __restrict__ Wsrc,
                                                         short* __restrict__ WT,
                                                         int K, int N) {
    __shared__ float t[32][33];
    int tx = threadIdx.x & 31, ty = threadIdx.x >> 5;   // ty 0..7
    int n0 = blockIdx.x * 32, k0 = blockIdx.y * 32;
#pragma unroll
    for (int i = 0; i < 4; ++i)
        t[ty + 8 * i][tx] = Wsrc[(size_t)(k0 + ty + 8 * i) * N + n0 + tx];
    __syncthreads();
#pragma unroll
    for (int i = 0; i < 4; ++i)
        WT[(size_t)(n0 + ty + 8 * i) * K + k0 + tx] = (short)f2b(t[tx][ty + 8 * i]);
}

// ---------------------------------------------------------------------------
// 256x256 bf16 MFMA GEMM, tile-ahead ds_read pipelining:
//   All 24 fragment ds_reads for tile t+1 are issued at the END of tile t
//   (12 after the boundary barrier, overlapping burst4's MFMA; 12 after
//   burst4). During tile t+1's 4 MFMA bursts the compiler's counted lgkmcnt
//   finds data resident -> LDS drain hides under MFMA instead of
//   serializing with it (r12 PMC: reads+MFMA serialized, MfmaUtil 32%).
//   A double-buffered, B triple-buffered (160 KiB LDS); counted vmcnt(4) at
//   the boundary (B(t+2) stays in flight). XOR-swizzled LDS (0 conflicts).
//   NORM: fused per-head RMSNorm + RoPE epilogue for columns < 2048 (q,k).
// ---------------------------------------------------------------------------
template<typename CT, bool NORM>
__global__ __launch_bounds__(512) void gemm8ph(
        const short* __restrict__ A, const short* __restrict__ BT,
        const float* __restrict__ bias, CT* __restrict__ C,
        int M, int N, int K, int NX,
        const float* __restrict__ qw, const float* __restrict__ kw,
        const float* __restrict__ cos_t, const float* __restrict__ sin_t) {
    __shared__ short As[2][256 * 64];   // 64 KiB
    __shared__ short Bs[3][256 * 64];   // 96 KiB

    const int tid  = threadIdx.x;
    const int w    = tid >> 6;           // 0..7
    const int lane = tid & 63;
    const int l15  = lane & 15, lg = lane >> 4;
    const int wm = w >> 2, wn = w & 3;   // wave grid 2(M) x 4(N)

    const int nwg  = gridDim.x;
    const int cpx  = nwg >> 3;
    const int wgid = (blockIdx.x & 7) * cpx + (blockIdx.x >> 3);
    const int bx = wgid % NX, by = wgid / NX;
    const int m0 = by * 256, n0 = bx * 256;

    const int NT = K >> 6;               // K-tiles of 64

    const int sgrow = w * 8 + (lane >> 3);            // + j*64
    const int ksrc  = (((lane & 7) ^ (lane >> 3)) * 8);

    auto stageA = [&](int t, int buf) {
        const size_t k0 = (size_t)t * 64;
#pragma unroll
        for (int j = 0; j < 4; ++j)
            gload16(A + (size_t)(m0 + j * 64 + sgrow) * K + k0 + ksrc,
                    &As[buf][(j * 64 + w * 8) * 64]);
    };
    auto stageB = [&](int t, int buf) {
        const size_t k0 = (size_t)t * 64;
#pragma unroll
        for (int j = 0; j < 4; ++j)
            gload16(BT + (size_t)(n0 + j * 64 + sgrow) * K + k0 + ksrc,
                    &Bs[buf][(j * 64 + w * 8) * 64]);
    };

    const int swz = l15 & 7;

    // fragment readers (all indices compile-time after unroll)
    auto rdA = [&](int buf, int mh, s8v (&dst)[4][2]) {
#pragma unroll
        for (int i = 0; i < 4; ++i) {
            int row = wm * 128 + mh * 64 + i * 16 + l15;
#pragma unroll
            for (int kk = 0; kk < 2; ++kk)
                dst[i][kk] = *(const s8v*)&As[buf][row * 64 + (((kk * 4 + lg) ^ swz) * 8)];
        }
    };
    auto rdB = [&](int buf, int nh, s8v (&dst)[4][2]) {
#pragma unroll
        for (int ni = 0; ni < 2; ++ni) {
            int row = wn * 64 + (nh * 2 + ni) * 16 + l15;
#pragma unroll
            for (int kk = 0; kk < 2; ++kk)
                dst[nh * 2 + ni][kk] = *(const s8v*)&Bs[buf][row * 64 + (((kk * 4 + lg) ^ swz) * 8)];
        }
    };

    // prologue: A0, B0, B1 in flight; wait A0,B0; read tile-0 fragments
    stageA(0, 0);
    stageB(0, 0);
    stageB(1, 1);
    wait_vm4();
    bar();

    s8v a0[4][2], a1[4][2], bb[4][2];
    rdA(0, 0, a0);
    rdB(0, 0, bb);
    rdB(0, 1, bb);
    rdA(0, 1, a1);

    f32x4 acc[8][4] = {};

    int bufB = 0;
    for (int t = 0; t < NT; ++t) {
        const int bufA  = t & 1;
        const int nbufB = (bufB == 2) ? 0 : bufB + 1;   // (t+1)%3
        const int sbufB = (nbufB == 2) ? 0 : nbufB + 1; // (t+2)%3

        if (t + 1 < NT) stageA(t + 1, bufA ^ 1);
        if (t + 2 < NT) stageB(t + 2, sbufB);

        // burst1: mh0 x ni0/1
        __builtin_amdgcn_s_setprio(1);
#pragma unroll
        for (int i = 0; i < 4; ++i)
#pragma unroll
            for (int ni = 0; ni < 2; ++ni)
#pragma unroll
                for (int kk = 0; kk < 2; ++kk)
                    acc[i][ni] = mfma_bf16(a0[i][kk], bb[ni][kk], acc[i][ni]);
        __builtin_amdgcn_s_setprio(0);

        // burst2: mh0 x ni2/3
        __builtin_amdgcn_s_setprio(1);
#pragma unroll
        for (int i = 0; i < 4; ++i)
#pragma unroll
            for (int ni = 2; ni < 4; ++ni)
#pragma unroll
                for (int kk = 0; kk < 2; ++kk)
                    acc[i][ni] = mfma_bf16(a0[i][kk], bb[ni][kk], acc[i][ni]);
        __builtin_amdgcn_s_setprio(0);

        // burst3: mh1 x ni0/1  (last use of bb[0..1]; a1 completion forces
        // lgkmcnt(0) here -> all tile-t reads done before the barrier below)
        __builtin_amdgcn_s_setprio(1);
#pragma unroll
        for (int i = 0; i < 4; ++i)
#pragma unroll
            for (int ni = 0; ni < 2; ++ni)
#pragma unroll
                for (int kk = 0; kk < 2; ++kk)
                    acc[4 + i][ni] = mfma_bf16(a1[i][kk], bb[ni][kk], acc[4 + i][ni]);
        __builtin_amdgcn_s_setprio(0);

        // boundary: A(t+1),B(t+1) complete; B(t+2) stays in flight
        if (t < NT - 2) wait_vm4(); else wait_vm0();
        bar();

        // first half of tile t+1's reads (a0, b01 regs are dead)
        if (t + 1 < NT) {
            rdA(bufA ^ 1, 0, a0);
            rdB(nbufB, 0, bb);
        }

        // burst4: mh1 x ni2/3 (uses a1, bb[2..3] only) — overlaps read drain
        __builtin_amdgcn_s_setprio(1);
#pragma unroll
        for (int i = 0; i < 4; ++i)
#pragma unroll
            for (int ni = 2; ni < 4; ++ni)
#pragma unroll
                for (int kk = 0; kk < 2; ++kk)
                    acc[4 + i][ni] = mfma_bf16(a1[i][kk], bb[ni][kk], acc[4 + i][ni]);
        __builtin_amdgcn_s_setprio(0);

        // second half of tile t+1's reads
        if (t + 1 < NT) {
            rdB(nbufB, 1, bb);
            rdA(bufA ^ 1, 1, a1);
        }
        bufB = nbufB;
    }

    // ---------------- epilogue ----------------
    const int colbase = n0 + wn * 64;
    if constexpr (NORM) {
        if (colbase < 2048) {
            const float* nw = (colbase < 1024) ? qw : kw;
            float wv[4], bv[4];
#pragma unroll
            for (int ni = 0; ni < 4; ++ni) {
                wv[ni] = nw[16 * ni + l15];
                bv[ni] = bias[colbase + 16 * ni + l15];
            }
#pragma unroll
            for (int mi = 0; mi < 8; ++mi) {
#pragma unroll
                for (int r = 0; r < 4; ++r) {
                    int row = m0 + wm * 128 + mi * 16 + lg * 4 + r;
                    int s = row & (S_ - 1);
                    float v[4];
#pragma unroll
                    for (int ni = 0; ni < 4; ++ni) v[ni] = acc[mi][ni][r] + bv[ni];
                    float ss = v[0]*v[0] + v[1]*v[1] + v[2]*v[2] + v[3]*v[3];
                    ss += __shfl_xor(ss, 1);
                    ss += __shfl_xor(ss, 2);
                    ss += __shfl_xor(ss, 4);
                    ss += __shfl_xor(ss, 8);
                    float rms = rsqrtf(ss * (1.0f / 64.0f) + 1e-6f);
                    float xn[4];
#pragma unroll
                    for (int ni = 0; ni < 4; ++ni) xn[ni] = v[ni] * rms * wv[ni];
#pragma unroll
                    for (int ni = 0; ni < 4; ++ni) {
                        int d = 16 * ni + l15;
                        float c  = cos_t[s * 64 + d];
                        float sn = sin_t[s * 64 + d];
                        float rot = (ni < 2) ? -xn[ni + 2] : xn[ni - 2];
                        C[(size_t)row * N + colbase + d] = (short)f2b(xn[ni] * c + rot * sn);
                    }
                }
            }
            return;
        }
    }
#pragma unroll
    for (int ni = 0; ni < 4; ++ni) {
        float bvv = bias[colbase + 16 * ni + l15];
#pragma unroll
        for (int mi = 0; mi < 8; ++mi) {
#pragma unroll
            for (int r = 0; r < 4; ++r) {
                size_t row = (size_t)(m0 + wm * 128 + mi * 16 + lg * 4 + r);
                int    col = colbase + 16 * ni + l15;
                float v = acc[mi][ni][r] + bvv;
                if constexpr (sizeof(CT) == 4) C[row * N + col] = v;
                else                           C[row * N + col] = (short)f2b(v);
            }
        }
    }
}

// ---------------------------------------------------------------------------
// MFMA flash attention, 32x32x16 dataflow (round-11 version, unchanged):
// zero-shuffle PV (pi-permuted Vt), f32 denominator (4 acc), max3, defer-max.
// ---------------------------------------------------------------------------
__global__ __launch_bounds__(256) void attn_mfma(const short* __restrict__ qkv,
                                                 short* __restrict__ attn) {
    __shared__ ushort_t pool[9216];            // 18 KiB: Ks[64][72] | Vt[64][72]
    ushort_t* Ks = pool;                       // [key][d], pitch 72
    ushort_t* Vt = pool + 4608;                // [d][key-slot], pitch 72

    const float SC  = 0.18033688011112042f;    // 0.125 * log2(e)
    const float THR = 11.0f;

    const int tid  = threadIdx.x;
    const int w    = tid >> 6;
    const int lane = tid & 63;
    const int l31  = lane & 31, l5 = lane >> 5;

    const int bid = blockIdx.x;
    const int xcd = bid & 7;
    const int jj_ = bid >> 3;
    const int bh  = xcd * 32 + (jj_ & 31);
    const int b   = bh >> 4, h = bh & 15;
    const int q0  = (jj_ >> 5) * 128;

    const short* qbase = qkv + (size_t)b * S_ * TDIM + h * HD_;
    const short* kb_ = qbase + DIM_;
    const short* vb_ = qbase + 2 * DIM_;

    s8v qf[4];
#pragma unroll
    for (int kc = 0; kc < 4; ++kc)
        qf[kc] = *(const s8v*)(qbase + (size_t)(q0 + w * 32 + l31) * TDIM + kc * 16 + l5 * 8);

    f32x16 of0 = {}, of1 = {};
    float m_s = -1e30f, l_s = 0.f;

    const int kr   = tid >> 3;
    const int kp8  = (tid & 7) * 8;
    const int vkp  = tid >> 3;         // key pair base k2 = 2*vkp
    const int va   = tid & 7;
    const int vp8  = va * 8;
    const int k2    = 2 * vkp;
    const int kperm = (k2 & 0x33) | ((k2 & 4) << 1) | ((k2 & 8) >> 1);
    const int vcol  = kperm ^ ((va & 3) << 4);
    const int vsw   = ((l31 >> 3) & 3) << 4;   // read-side XOR (slot space)

    s8v kA, kB, vA, vB;
    auto prefetch = [&](int kt) {
        const short* kbt = kb_ + (size_t)kt * 64 * TDIM;
        const short* vbt = vb_ + (size_t)kt * 64 * TDIM;
        kA = *(const s8v*)(kbt + (size_t)kr * TDIM + kp8);
        kB = *(const s8v*)(kbt + (size_t)(kr + 32) * TDIM + kp8);
        vA = *(const s8v*)(vbt + (size_t)k2 * TDIM + vp8);
        vB = *(const s8v*)(vbt + (size_t)(k2 + 1) * TDIM + vp8);
    };
    prefetch(0);

    for (int kt = 0; kt < 16; ++kt) {
        *(s8v*)&Ks[kr * 72 + kp8]        = kA;
        *(s8v*)&Ks[(kr + 32) * 72 + kp8] = kB;
#pragma unroll
        for (int j = 0; j < 8; ++j) {
            uint_t pk = (ushort_t)vA[j] | ((uint_t)(ushort_t)vB[j] << 16);
            *(uint_t*)&Vt[(vp8 + j) * 72 + vcol] = pk;
        }
        __syncthreads();

        if (kt < 15) prefetch(kt + 1);

        // ---- QK^T (swapped): st{0,1} = S^T[key-block][q] 32x32 frags
        f32x16 st0 = {}, st1 = {};
        __builtin_amdgcn_s_setprio(1);
#pragma unroll
        for (int kc = 0; kc < 4; ++kc) {
            s8v kf0 = *(const s8v*)&Ks[l31 * 72 + kc * 16 + l5 * 8];
            s8v kf1 = *(const s8v*)&Ks[(32 + l31) * 72 + kc * 16 + l5 * 8];
            st0 = mfma32_bf16(kf0, qf[kc], st0);
            st1 = mfma32_bf16(kf1, qf[kc], st1);
        }
        __builtin_amdgcn_s_setprio(0);

        // ---- row max: two independent v_max3 chains + one cross-half shfl
        float ma = fmaxf(st0[0], st1[0]);
        float mb = fmaxf(st0[8], st1[8]);
#pragma unroll
        for (int r = 1; r < 8; ++r) {
            ma = max3f(st0[r],     st1[r],     ma);
            mb = max3f(st0[8 + r], st1[8 + r], mb);
        }
        float mx = fmaxf(ma, mb);
        mx = fmaxf(mx, __shfl_xor(mx, 32));
        float mxs = mx * SC;

        if (!__all(mxs <= m_s + THR)) {          // wave-uniform, rare
            float mnew  = fmaxf(m_s, mxs);
            float alpha = exp2f(m_s - mnew);
            m_s = mnew;
            l_s *= alpha;
#pragma unroll
            for (int r = 0; r < 16; ++r) { of0[r] *= alpha; of1[r] *= alpha; }
        }

        // ---- P = exp2(st*SC - m); f32 denominator, 4 independent accumulators
        float la = 0.f, lb = 0.f, lc = 0.f, ld = 0.f;
#pragma unroll
        for (int r = 0; r < 16; r += 2) {
            float p00 = exp2f(__builtin_fmaf(st0[r],     SC, -m_s));
            float p01 = exp2f(__builtin_fmaf(st0[r + 1], SC, -m_s));
            float p10 = exp2f(__builtin_fmaf(st1[r],     SC, -m_s));
            float p11 = exp2f(__builtin_fmaf(st1[r + 1], SC, -m_s));
            st0[r] = p00; st0[r + 1] = p01;
            st1[r] = p10; st1[r + 1] = p11;
            la += p00; lb += p01; lc += p10; ld += p11;
        }
        float ls = (la + lb) + (lc + ld);
        ls += __shfl_xor(ls, 32);
        l_s += ls;

        // ---- P -> bf16 pairs
        uint_t P20[8], P21[8];
#pragma unroll
        for (int i = 0; i < 8; ++i) {
            P20[i] = cvt_pk_bf16(st0[2 * i], st0[2 * i + 1]);
            P21[i] = cvt_pk_bf16(st1[2 * i], st1[2 * i + 1]);
        }

        // ---- PV: zero-shuffle B-frags (pi-permuted Vt slots)
        __builtin_amdgcn_s_setprio(1);
#pragma unroll
        for (int kb = 0; kb < 2; ++kb) {
            const uint_t* P2 = kb ? P21 : P20;
#pragma unroll
            for (int c = 0; c < 2; ++c) {
                union { uint_t u[4]; s8v v; } pf;
                pf.u[0] = P2[4 * c + 0];
                pf.u[1] = P2[4 * c + 1];
                pf.u[2] = P2[4 * c + 2];
                pf.u[3] = P2[4 * c + 3];

                int kcol = (kb * 32 + c * 16 + l5 * 8) ^ vsw;
                s8v vf0 = *(const s8v*)&Vt[l31 * 72 + kcol];
                s8v vf1 = *(const s8v*)&Vt[(32 + l31) * 72 + kcol];
                of0 = mfma32_bf16(vf0, pf.v, of0);
                of1 = mfma32_bf16(vf1, pf.v, of1);
            }
        }
        __builtin_amdgcn_s_setprio(0);
        __syncthreads();
    }

    // ---- epilogue: O^T -> LDS transpose -> coalesced 16B stores
    float inv = 1.0f / l_s;
    ushort_t* OL = pool + w * 2304;        // per-wave [32 q][72], wave-private
#pragma unroll
    for (int r = 0; r < 16; ++r) {
        int d = (r & 3) + 8 * (r >> 2) + 4 * l5;
        OL[l31 * 72 + d]      = f2b(of0[r] * inv);
        OL[l31 * 72 + 32 + d] = f2b(of1[r] * inv);
    }
#pragma unroll
    for (int i = 0; i < 4; ++i) {
        int idx = lane + i * 64;
        int row = idx >> 3, ch = idx & 7;
        *(s8v*)&attn[((size_t)b * S_ + q0 + w * 32 + row) * DIM_ + h * HD_ + ch * 8] =
            *(const s8v*)&OL[row * 72 + ch * 8];
    }
}

// ---------------------------------------------------------------------------
extern "C" void kernel_launch(void* const* d_in, const int* in_sizes, int n_in,
                              void* d_out, int out_size, void* d_ws, size_t ws_size,
                              hipStream_t stream) {
    const float* x        = (const float*)d_in[0];
    const float* w_qkv    = (const float*)d_in[1];
    const float* b_qkv    = (const float*)d_in[2];
    const float* q_norm_w = (const float*)d_in[3];
    const float* k_norm_w = (const float*)d_in[4];
    const float* w_out    = (const float*)d_in[5];
    const float* b_out    = (const float*)d_in[6];
    float* out = (float*)d_out;

    const size_t OFF_QKV = 0;                          //  96 MiB: qkv bf16
    const size_t OFF_ATT = 100663296;                  //  32 MiB: attn bf16
    const size_t OFF_XB  = OFF_ATT + 33554432;         //  32 MiB: x bf16
    const size_t OFF_WQ  = OFF_XB + 33554432;          //   6 MiB: w_qkv^T bf16
    const size_t OFF_WO  = OFF_WQ + 6291456;           //   2 MiB: w_out^T bf16
    const size_t OFF_CT  = OFF_WO + 2097152;           // 256 KiB: cos table
    const size_t OFF_ST  = OFF_CT + 262144;            // 256 KiB: sin table
    const size_t NEED    = OFF_ST + 262144;

    if (ws_size < NEED) {
        hipMemsetAsync(d_out, 0, (size_t)out_size * sizeof(float), stream);
        return;
    }

    char* ws = (char*)d_ws;
    short* qkv   = (short*)(ws + OFF_QKV);
    short* attnb = (short*)(ws + OFF_ATT);
    short* xb    = (short*)(ws + OFF_XB);
    short* wqkvT = (short*)(ws + OFF_WQ);
    short* woutT = (short*)(ws + OFF_WO);
    float* cos_t = (float*)(ws + OFF_CT);
    float* sin_t = (float*)(ws + OFF_ST);

    // 0: tables, conversions, weight transposes
    rope_tables<<<dim3(256), dim3(256), 0, stream>>>(cos_t, sin_t);
    f32_to_bf16_vec<<<dim3(8192), dim3(256), 0, stream>>>(x, xb, 2097152);
    transpose_to_bf16<<<dim3(96, 32), dim3(256), 0, stream>>>(w_qkv, wqkvT, 1024, 3072);
    transpose_to_bf16<<<dim3(32, 32), dim3(256), 0, stream>>>(w_out, woutT, 1024, 1024);

    // 1: qkv = x @ w_qkv + b_qkv, fused RMSNorm+RoPE epilogue on q,k columns.
    gemm8ph<short, true><<<dim3(768), dim3(512), 0, stream>>>(
        xb, wqkvT, b_qkv, qkv, 16384, 3072, 1024, 12,
        q_norm_w, k_norm_w, cos_t, sin_t);

    // 2: flash attention -> attnb (bf16)
    attn_mfma<<<dim3(2048), dim3(256), 0, stream>>>(qkv, attnb);

    // 3: out = attn @ w_out + b_out (fp32 out)
    gemm8ph<float, false><<<dim3(256), dim3(512), 0, stream>>>(
        attnb, woutT, b_out, out, 16384, 1024, 1024, 4,
        nullptr, nullptr, nullptr, nullptr);
}